// Round 3
// baseline (3396.880 us; speedup 1.0000x reference)
//
#include <hip/hip_runtime.h>
#include <math.h>

namespace {

constexpr int Bn = 8, Sn = 1024, Dn = 768, Hn = 12, DHn = 64, Fn = 3072;
constexpr int Mrows = Bn * Sn;  // 8192 token rows

typedef __attribute__((ext_vector_type(8))) short bfrag;   // 8 bf16 = 4 VGPR
typedef __attribute__((ext_vector_type(4))) float f4acc;   // 4 f32 acc

typedef const __attribute__((address_space(1))) unsigned int* gas_t;
typedef __attribute__((address_space(3))) unsigned int* las_t;

__device__ __forceinline__ void gload16(const ushort* g, ushort* l) {
  __builtin_amdgcn_global_load_lds((gas_t)g, (las_t)l, 16, 0, 0);
}

__device__ __forceinline__ f4acc mfma16(bfrag a, bfrag b, f4acc c) {
  return __builtin_amdgcn_mfma_f32_16x16x32_bf16(a, b, c, 0, 0, 0);
}

// split fp32 -> bf16 hi + bf16 lo (truncation; residual ~2^-16 rel)
__device__ __forceinline__ void bsplit(float x, ushort& h, ushort& l) {
  union { float f; unsigned u; } a; a.f = x;
  const ushort hi = (ushort)(a.u >> 16);
  union { unsigned u; float f; } hf; hf.u = (unsigned)hi << 16;
  union { float f; unsigned u; } b; b.f = x - hf.f;
  h = hi; l = (ushort)(b.u >> 16);
}

// ---------------------------------------------------------------------------
// Elementwise fp32 -> (hi, lo) bf16 split, vectorized.
// ---------------------------------------------------------------------------
__global__ __launch_bounds__(256) void split_rows(const float4* __restrict__ X,
                                                  ushort* __restrict__ H,
                                                  ushort* __restrict__ L,
                                                  int n4) {
  int i = blockIdx.x * 256 + threadIdx.x;
  const int stride = gridDim.x * 256;
  for (; i < n4; i += stride) {
    const float4 v = X[i];
    ushort h0, l0, h1, l1, h2, l2, h3, l3;
    bsplit(v.x, h0, l0); bsplit(v.y, h1, l1);
    bsplit(v.z, h2, l2); bsplit(v.w, h3, l3);
    ushort4 hv; hv.x = h0; hv.y = h1; hv.z = h2; hv.w = h3;
    ushort4 lv; lv.x = l0; lv.y = l1; lv.z = l2; lv.w = l3;
    *(ushort4*)&H[(size_t)i * 4] = hv;
    *(ushort4*)&L[(size_t)i * 4] = lv;
  }
}

// ---------------------------------------------------------------------------
// W[K][N] fp32 -> Th[N][K], Tl[N][K] bf16 (transpose + split). 64x64 tiles.
// ---------------------------------------------------------------------------
__global__ __launch_bounds__(256) void transpose_split(
    const float* __restrict__ W, ushort* __restrict__ Th,
    ushort* __restrict__ Tl, int K, int N) {
  __shared__ float t[64][65];
  const int k0 = blockIdx.y * 64, n0 = blockIdx.x * 64;
  const int c = threadIdx.x & 63, rg = threadIdx.x >> 6;
#pragma unroll
  for (int rr = 0; rr < 16; ++rr) {
    const int r = rg * 16 + rr;
    t[r][c] = W[(size_t)(k0 + r) * N + n0 + c];
  }
  __syncthreads();
#pragma unroll
  for (int rr = 0; rr < 16; ++rr) {
    const int n = rg * 16 + rr;
    const float x = t[c][n];
    ushort h16, l16;
    bsplit(x, h16, l16);
    const size_t o = (size_t)(n0 + n) * K + k0 + c;
    Th[o] = h16;
    Tl[o] = l16;
  }
}

// ---------------------------------------------------------------------------
// bf16x3 split MFMA GEMM: C[M,cols] = epi(A @ B^T + bias [+ res])
//   A: [M][Kd] as hi/lo bf16 (K-major).  B: [cols][Kd] hi/lo bf16 (K-major,
//   i.e. W pre-transposed).  128x128 tile, BK=32, 4 waves (2x2 of 64x64).
// LDS chunk-major: 16B chunk index p = kg*128 + row -> linear staging via
// global_load_lds AND ~conflict-free ds_read_b128 (quarter-wave reads a
// contiguous 256B span).
// MODE 0: QKV (grid.x=18; B/bias/C selected by bn/6)     -> C fp32
// MODE 1: Wo  (+res, fp32 C + hi/lo split out)           -> out1
// MODE 2: W1  (erf-GELU, hi-only bf16 out, N=3072)       -> h_hi
// MODE 3: W2  (+res, fp32 C; A single bf16: ASPLIT=false)-> out1 in place
// ---------------------------------------------------------------------------
template <int MODE, bool ASPLIT>
__global__ __launch_bounds__(256) void mfma_gemm(
    const ushort* __restrict__ Ah, const ushort* __restrict__ Al,
    const ushort* __restrict__ B0h, const ushort* __restrict__ B0l,
    const ushort* __restrict__ B1h, const ushort* __restrict__ B1l,
    const ushort* __restrict__ B2h, const ushort* __restrict__ B2l,
    const float* __restrict__ bias0, const float* __restrict__ bias1,
    const float* __restrict__ bias2, const float* __restrict__ res,
    float* __restrict__ C0, float* __restrict__ C1, float* __restrict__ C2,
    ushort* __restrict__ Chi, ushort* __restrict__ Clo, int Kd) {
  constexpr int NARR = ASPLIT ? 4 : 3;  // 0=Ah 1=Bh 2=Bl [3=Al]
  __shared__ ushort lds[NARR][4096];    // 8 KB each

  const int tid = threadIdx.x;
  const int w = tid >> 6, l = tid & 63;
  const int wm = w >> 1, wn = w & 1;
  const int r16 = l & 15, kg = l >> 4;
  const int bn = blockIdx.x, bm = blockIdx.y;

  const ushort* Bh = B0h;
  const ushort* Bl = B0l;
  const float* bias = bias0;
  float* Cout = C0;
  int colBase = bn * 128, bRow0 = bn * 128;
  if (MODE == 0) {
    const int sel = bn / 6;
    Bh = sel == 0 ? B0h : sel == 1 ? B1h : B2h;
    Bl = sel == 0 ? B0l : sel == 1 ? B1l : B2l;
    bias = sel == 0 ? bias0 : sel == 1 ? bias1 : bias2;
    Cout = sel == 0 ? C0 : sel == 1 ? C1 : C2;
    colBase = (bn % 6) * 128;
    bRow0 = colBase;
  }
  const int aRow0 = bm * 128;
  const int N = (MODE == 2) ? Fn : Dn;

  f4acc acc[4][4] = {};

  for (int k0 = 0; k0 < Kd; k0 += 32) {
    __syncthreads();  // previous tile fully consumed
#pragma unroll
    for (int ii = 0; ii < 2; ++ii) {
      const int row = ii * 64 + l;
      const size_t aoff = (size_t)(aRow0 + row) * Kd + k0 + w * 8;
      const size_t boff = (size_t)(bRow0 + row) * Kd + k0 + w * 8;
      const int ldsOff = (w * 128 + ii * 64) * 8;
      gload16(Ah + aoff, &lds[0][ldsOff]);
      gload16(Bh + boff, &lds[1][ldsOff]);
      gload16(Bl + boff, &lds[2][ldsOff]);
      if (ASPLIT) gload16(Al + aoff, &lds[NARR - 1][ldsOff]);
    }
    __syncthreads();  // compiler drains vmcnt before barrier -> tile ready

    bfrag ah[4], al[4], bh[4], bl[4];
#pragma unroll
    for (int m = 0; m < 4; ++m) {
      const int p = (kg * 128 + wm * 64 + m * 16 + r16) * 8;
      ah[m] = *(const bfrag*)&lds[0][p];
      if (ASPLIT) al[m] = *(const bfrag*)&lds[NARR - 1][p];
    }
#pragma unroll
    for (int n = 0; n < 4; ++n) {
      const int p = (kg * 128 + wn * 64 + n * 16 + r16) * 8;
      bh[n] = *(const bfrag*)&lds[1][p];
      bl[n] = *(const bfrag*)&lds[2][p];
    }
#pragma unroll
    for (int m = 0; m < 4; ++m)
#pragma unroll
      for (int n = 0; n < 4; ++n) {
        acc[m][n] = mfma16(ah[m], bh[n], acc[m][n]);
        acc[m][n] = mfma16(ah[m], bl[n], acc[m][n]);
        if (ASPLIT) acc[m][n] = mfma16(al[m], bh[n], acc[m][n]);
      }
  }

  float bc[4];
#pragma unroll
  for (int n = 0; n < 4; ++n) bc[n] = bias[colBase + wn * 64 + n * 16 + r16];

#pragma unroll
  for (int m = 0; m < 4; ++m)
#pragma unroll
    for (int e = 0; e < 4; ++e) {
      const int grow = aRow0 + wm * 64 + m * 16 + (l >> 4) * 4 + e;
#pragma unroll
      for (int n = 0; n < 4; ++n) {
        const int gcol = colBase + wn * 64 + n * 16 + r16;
        const size_t o = (size_t)grow * N + gcol;
        float v = acc[m][n][e] + bc[n];
        if (MODE == 0) {
          Cout[o] = v;
        } else if (MODE == 1) {
          v += res[o];
          Cout[o] = v;
          ushort h16, l16;
          bsplit(v, h16, l16);
          Chi[o] = h16;
          Clo[o] = l16;
        } else if (MODE == 2) {
          v = 0.5f * v * (1.f + erff(v * 0.70710678118654752f));
          ushort h16, l16;
          bsplit(v, h16, l16);
          Chi[o] = h16;  // hi-only (ws budget); W2 runs ASPLIT=false
        } else {  // MODE 3
          v += res[o];
          Cout[o] = v;
        }
      }
    }
}

// ---------------------------------------------------------------------------
// Fused attention: per block = (b, h, 8 query rows), 256 thr, 4 blocks/CU.
// scores(strided K reads) -> softmax+attn write -> PV outer-product (lane=d,
// coalesced V rows, P broadcast from LDS) -> cross-wave reduce in s_sc overlay.
// ---------------------------------------------------------------------------
__global__ __launch_bounds__(256, 4) void attn_kernel(
    const float* __restrict__ q, const float* __restrict__ k,
    const float* __restrict__ v, const float* __restrict__ mask,
    const float* __restrict__ adjoin, float* __restrict__ attn,
    float* __restrict__ ctx) {
  __shared__ float s_sc[8][1024];  // 32 KB score tile (rows 0-1 reused as s_red)
  __shared__ float s_q[8][64];     // 2 KB
  __shared__ float s_inv[8];

  const int tid = threadIdx.x;
  const int bid = blockIdx.x;
  const int it = bid & 127;
  const int h = (bid >> 7) % Hn;
  const int b = bid / (128 * Hn);
  const int i0 = it * 8;
  const int w = tid >> 6, l = tid & 63;

  if (tid < 128) {
    const int row = tid >> 4, d4 = tid & 15;
    *(float4*)&s_q[row][d4 * 4] =
        *(const float4*)(q + (size_t)(b * Sn + i0 + row) * Dn + h * DHn + d4 * 4);
  }
  __syncthreads();

  const float* kbase = k + (size_t)b * Sn * Dn + h * DHn;
  const float* vbase = v + (size_t)b * Sn * Dn + h * DHn;

  // ---- scores ----
  for (int c = 0; c < 4; ++c) {
    const int j = (w << 8) + (c << 6) + l;
    const float4* k4 = (const float4*)(kbase + (size_t)j * Dn);
    float dot[8];
#pragma unroll
    for (int r = 0; r < 8; ++r) dot[r] = 0.f;
#pragma unroll
    for (int f = 0; f < 16; ++f) {
      const float4 kv = k4[f];
#pragma unroll
      for (int r = 0; r < 8; ++r) {
        const float4 qv = *(const float4*)&s_q[r][f * 4];
        dot[r] += qv.x * kv.x + qv.y * kv.y + qv.z * kv.z + qv.w * kv.w;
      }
    }
    const float mval = mask[b * Sn + j] * (-1e9f);
#pragma unroll
    for (int r = 0; r < 8; ++r) {
      const float adj = adjoin[((size_t)b * Sn + i0 + r) * Sn + j];
      s_sc[r][j] = dot[r] * 0.125f + mval + adj;
    }
  }
  __syncthreads();

  // ---- softmax (wave w: rows 2w, 2w+1) + normalized attn write ----
  const size_t attnrow_base = ((size_t)(b * Hn + h) * Sn + i0) * Sn;
#pragma unroll
  for (int rr = 0; rr < 2; ++rr) {
    const int r = 2 * w + rr;
    float m = -INFINITY;
    for (int c = 0; c < 16; ++c) m = fmaxf(m, s_sc[r][(c << 6) + l]);
#pragma unroll
    for (int off = 32; off > 0; off >>= 1) m = fmaxf(m, __shfl_xor(m, off));
    float ssum = 0.f;
    for (int c = 0; c < 16; ++c) {
      const float e = expf(s_sc[r][(c << 6) + l] - m);
      s_sc[r][(c << 6) + l] = e;  // unnormalized in LDS
      ssum += e;
    }
#pragma unroll
    for (int off = 32; off > 0; off >>= 1) ssum += __shfl_xor(ssum, off);
    const float inv = 1.0f / ssum;
    if (l == 0) s_inv[r] = inv;
    for (int c = 0; c < 16; ++c) {
      const int j = (c << 6) + l;
      attn[attnrow_base + (size_t)r * Sn + j] = s_sc[r][j] * inv;
    }
  }
  __syncthreads();

  // ---- PV outer-product: lane l = d, wave w covers j in [256w, 256w+256) ----
  float pv[8];
#pragma unroll
  for (int r = 0; r < 8; ++r) pv[r] = 0.f;
  const float* vq = vbase + (size_t)(w << 8) * Dn + l;
  for (int jj = 0; jj < 256; jj += 2) {
    const int j = (w << 8) + jj;
    const float va = vq[(size_t)jj * Dn];
    const float vb2 = vq[(size_t)(jj + 1) * Dn];
#pragma unroll
    for (int r = 0; r < 8; ++r) {
      const float2 p2 = *(const float2*)&s_sc[r][j];
      pv[r] += p2.x * va + p2.y * vb2;
    }
  }
  __syncthreads();  // all s_sc reads done before overlay

  float* s_red = &s_sc[0][0];  // [4][8][64] overlay on rows 0-1
#pragma unroll
  for (int r = 0; r < 8; ++r) s_red[(w * 8 + r) * 64 + l] = pv[r];
  __syncthreads();

#pragma unroll
  for (int o = 0; o < 2; ++o) {
    const int idx = tid + (o << 8);
    const int r = idx >> 6, d = idx & 63;
    const float val = (s_red[(0 * 8 + r) * 64 + d] + s_red[(1 * 8 + r) * 64 + d] +
                       s_red[(2 * 8 + r) * 64 + d] + s_red[(3 * 8 + r) * 64 + d]) *
                      s_inv[r];
    ctx[(size_t)(b * Sn + i0 + r) * Dn + h * DHn + d] = val;
  }
}

// ---------------------------------------------------------------------------
// LayerNorm over last dim (768), one block per row.
// ---------------------------------------------------------------------------
__global__ __launch_bounds__(256) void ln_kernel(
    const float* __restrict__ xin, const float* __restrict__ gamma,
    const float* __restrict__ beta, float* __restrict__ out) {
  const int row = blockIdx.x;
  const float* xr = xin + (size_t)row * Dn;
  const int tid = threadIdx.x;
  const float v0 = xr[tid];
  const float v1 = xr[tid + 256];
  const float v2 = xr[tid + 512];
  float s = v0 + v1 + v2;
  float s2 = v0 * v0 + v1 * v1 + v2 * v2;
#pragma unroll
  for (int off = 32; off > 0; off >>= 1) {
    s += __shfl_xor(s, off);
    s2 += __shfl_xor(s2, off);
  }
  __shared__ float red[2][4];
  const int w = tid >> 6, l = tid & 63;
  if (l == 0) { red[0][w] = s; red[1][w] = s2; }
  __syncthreads();
  s = red[0][0] + red[0][1] + red[0][2] + red[0][3];
  s2 = red[1][0] + red[1][1] + red[1][2] + red[1][3];
  const float mu = s * (1.f / 768.f);
  const float var = s2 * (1.f / 768.f) - mu * mu;
  const float inv = 1.0f / sqrtf(var + 1e-6f);
  out[(size_t)row * Dn + tid] = (v0 - mu) * inv * gamma[tid] + beta[tid];
  out[(size_t)row * Dn + tid + 256] =
      (v1 - mu) * inv * gamma[tid + 256] + beta[tid + 256];
  out[(size_t)row * Dn + tid + 512] =
      (v2 - mu) * inv * gamma[tid + 512] + beta[tid + 512];
}

}  // namespace

extern "C" void kernel_launch(void* const* d_in, const int* in_sizes, int n_in,
                              void* d_out, int out_size, void* d_ws,
                              size_t ws_size, hipStream_t stream) {
  const float* x = (const float*)d_in[0];
  const float* mask = (const float*)d_in[2];
  const float* adjoin = (const float*)d_in[3];
  const float* Wq = (const float*)d_in[4];
  const float* bq = (const float*)d_in[5];
  const float* Wk = (const float*)d_in[6];
  const float* bk = (const float*)d_in[7];
  const float* Wv = (const float*)d_in[8];
  const float* bv = (const float*)d_in[9];
  const float* Wo = (const float*)d_in[10];
  const float* bo = (const float*)d_in[11];
  const float* W1 = (const float*)d_in[12];
  const float* b1 = (const float*)d_in[13];
  const float* W2 = (const float*)d_in[14];
  const float* b2 = (const float*)d_in[15];
  const float* gamma2 = (const float*)d_in[16];
  const float* beta2 = (const float*)d_in[17];

  float* out2 = (float*)d_out;               // [B,S,D]
  float* attn = out2 + (size_t)Mrows * Dn;   // [B,H,S,S]

  const size_t SLOT = 25165824;  // 8192*768*4 bytes
  char* ws = (char*)d_ws;
  // ws slots (peak 116.3 MB):
  float* qb = (float*)(ws + 0 * SLOT);            // q -> out1 fp32
  float* kb = (float*)(ws + 1 * SLOT);            // k -> out1_hi/lo
  float* vb = (float*)(ws + 2 * SLOT);            // v -> ctx_hi/lo
  float* ctx = (float*)(ws + 3 * SLOT);           // ctx -> (h_hi tail)
  float* out1 = qb;
  ushort* out1_hi = (ushort*)(ws + 1 * SLOT);
  ushort* out1_lo = (ushort*)(ws + 1 * SLOT + SLOT / 2);
  ushort* ctx_hi = (ushort*)(ws + 2 * SLOT);
  ushort* ctx_lo = (ushort*)(ws + 2 * SLOT + SLOT / 2);
  ushort* h_hi = (ushort*)(ws + 2 * SLOT);        // spans slots 2..3 (50.3 MB)
  char* wsW = ws + 4 * SLOT;                      // persistent weight area
  const size_t WDD = 768ull * 768 * 2;            // 1.18 MB
  const size_t WDF = 768ull * 3072 * 2;           // 4.72 MB
  ushort* wot_hi = (ushort*)(wsW);
  ushort* wot_lo = (ushort*)(wsW + WDD);
  ushort* w1t_hi = (ushort*)(wsW + 2 * WDD);
  ushort* w1t_lo = (ushort*)(wsW + 2 * WDD + WDF);
  ushort* w2t_hi = (ushort*)(wsW + 2 * WDD + 2 * WDF);
  ushort* w2t_lo = (ushort*)(wsW + 2 * WDD + 3 * WDF);

  // scratch inside d_out's attn region (402 MB; dead until attn_kernel runs)
  char* scr = (char*)attn;
  ushort* x_hi = (ushort*)(scr);
  ushort* x_lo = (ushort*)(scr + SLOT / 2);
  ushort* wqt_hi = (ushort*)(scr + SLOT);
  ushort* wqt_lo = (ushort*)(scr + SLOT + WDD);
  ushort* wkt_hi = (ushort*)(scr + SLOT + 2 * WDD);
  ushort* wkt_lo = (ushort*)(scr + SLOT + 3 * WDD);
  ushort* wvt_hi = (ushort*)(scr + SLOT + 4 * WDD);
  ushort* wvt_lo = (ushort*)(scr + SLOT + 5 * WDD);

  const dim3 blk(256);

  // 1) input splits + weight transpose-splits
  split_rows<<<dim3(2048), blk, 0, stream>>>((const float4*)x, x_hi, x_lo,
                                             Mrows * Dn / 4);
  transpose_split<<<dim3(12, 12), blk, 0, stream>>>(Wq, wqt_hi, wqt_lo, Dn, Dn);
  transpose_split<<<dim3(12, 12), blk, 0, stream>>>(Wk, wkt_hi, wkt_lo, Dn, Dn);
  transpose_split<<<dim3(12, 12), blk, 0, stream>>>(Wv, wvt_hi, wvt_lo, Dn, Dn);
  transpose_split<<<dim3(12, 12), blk, 0, stream>>>(Wo, wot_hi, wot_lo, Dn, Dn);
  transpose_split<<<dim3(48, 12), blk, 0, stream>>>(W1, w1t_hi, w1t_lo, Dn, Fn);
  transpose_split<<<dim3(12, 48), blk, 0, stream>>>(W2, w2t_hi, w2t_lo, Fn, Dn);

  // 2) fused QKV projection (bf16x3 MFMA)
  mfma_gemm<0, true><<<dim3(18, 64), blk, 0, stream>>>(
      x_hi, x_lo, wqt_hi, wqt_lo, wkt_hi, wkt_lo, wvt_hi, wvt_lo, bq, bk, bv,
      nullptr, qb, kb, vb, nullptr, nullptr, Dn);

  // 3) fused attention (writes attn -> d_out, ctx -> ws)
  attn_kernel<<<dim3(Bn * Hn * (Sn / 8)), blk, 0, stream>>>(qb, kb, vb, mask,
                                                            adjoin, attn, ctx);

  // 4) split ctx for Wo GEMM
  split_rows<<<dim3(2048), blk, 0, stream>>>((const float4*)ctx, ctx_hi, ctx_lo,
                                             Mrows * Dn / 4);

  // 5) out1 = x + ctx @ Wo + bo  (+ hi/lo split)
  mfma_gemm<1, true><<<dim3(6, 64), blk, 0, stream>>>(
      ctx_hi, ctx_lo, wot_hi, wot_lo, nullptr, nullptr, nullptr, nullptr, bo,
      nullptr, nullptr, x, out1, nullptr, nullptr, out1_hi, out1_lo, Dn);

  // 6) h_hi = bf16(gelu(out1 @ W1 + b1))
  mfma_gemm<2, true><<<dim3(24, 64), blk, 0, stream>>>(
      out1_hi, out1_lo, w1t_hi, w1t_lo, nullptr, nullptr, nullptr, nullptr, b1,
      nullptr, nullptr, nullptr, nullptr, nullptr, nullptr, h_hi, nullptr, Dn);

  // 7) out1 += h @ W2 + b2 (in place; A single-bf16)
  mfma_gemm<3, false><<<dim3(6, 64), blk, 0, stream>>>(
      h_hi, nullptr, w2t_hi, w2t_lo, nullptr, nullptr, nullptr, nullptr, b2,
      nullptr, nullptr, out1, out1, nullptr, nullptr, nullptr, nullptr, Fn);

  // 8) out2 = layernorm(out1)
  ln_kernel<<<dim3(Mrows), blk, 0, stream>>>(out1, gamma2, beta2, out2);
}

// Round 4
// 1245.985 us; speedup vs baseline: 2.7263x; 2.7263x over previous
//
#include <hip/hip_runtime.h>
#include <math.h>

namespace {

constexpr int Bn = 8, Sn = 1024, Dn = 768, Hn = 12, DHn = 64, Fn = 3072;
constexpr int Mrows = Bn * Sn;  // 8192 token rows

typedef __attribute__((ext_vector_type(8))) short bfrag;   // 8 bf16 = 4 VGPR
typedef __attribute__((ext_vector_type(4))) float f4acc;   // 4 f32 acc

typedef const __attribute__((address_space(1))) unsigned int* gas_t;
typedef __attribute__((address_space(3))) unsigned int* las_t;

__device__ __forceinline__ void gload16(const ushort* g, ushort* l) {
  __builtin_amdgcn_global_load_lds((gas_t)g, (las_t)l, 16, 0, 0);
}

__device__ __forceinline__ f4acc mfma16(bfrag a, bfrag b, f4acc c) {
  return __builtin_amdgcn_mfma_f32_16x16x32_bf16(a, b, c, 0, 0, 0);
}

// split fp32 -> bf16 hi + bf16 lo (truncation; residual ~2^-16 rel)
__device__ __forceinline__ void bsplit(float x, ushort& h, ushort& l) {
  union { float f; unsigned u; } a; a.f = x;
  const ushort hi = (ushort)(a.u >> 16);
  union { unsigned u; float f; } hf; hf.u = (unsigned)hi << 16;
  union { float f; unsigned u; } b; b.f = x - hf.f;
  h = hi; l = (ushort)(b.u >> 16);
}

__device__ __forceinline__ ushort rne_bf16(float x) {
  union { float f; unsigned u; } a; a.f = x;
  const unsigned r = a.u + 0x7FFF + ((a.u >> 16) & 1);
  return (ushort)(r >> 16);
}

__device__ __forceinline__ float bf2f(ushort x) {
  union { unsigned u; float f; } t; t.u = ((unsigned)x) << 16;
  return t.f;
}

// LDS XOR swizzles (write-side and read-side must match)
__device__ __forceinline__ int swz128(int row, int byteInRow) {  // 128B rows
  return row * 128 + (byteInRow ^ ((row & 7) << 4));
}
__device__ __forceinline__ int swz256(int row, int byteInRow) {  // 256B rows
  return row * 256 + (byteInRow ^ ((row & 7) << 4));
}
__device__ __forceinline__ int swzV128(int row, int byteInRow) { // key=(row>>3)&7
  return row * 128 + (byteInRow ^ (((row >> 3) & 7) << 4));
}

// ---------------------------------------------------------------------------
// Elementwise fp32 -> (hi, lo) bf16 split, vectorized.
// ---------------------------------------------------------------------------
__global__ __launch_bounds__(256) void split_rows(const float4* __restrict__ X,
                                                  ushort* __restrict__ H,
                                                  ushort* __restrict__ L,
                                                  int n4) {
  int i = blockIdx.x * 256 + threadIdx.x;
  const int stride = gridDim.x * 256;
  for (; i < n4; i += stride) {
    const float4 v = X[i];
    ushort h0, l0, h1, l1, h2, l2, h3, l3;
    bsplit(v.x, h0, l0); bsplit(v.y, h1, l1);
    bsplit(v.z, h2, l2); bsplit(v.w, h3, l3);
    ushort4 hv; hv.x = h0; hv.y = h1; hv.z = h2; hv.w = h3;
    ushort4 lv; lv.x = l0; lv.y = l1; lv.z = l2; lv.w = l3;
    *(ushort4*)&H[(size_t)i * 4] = hv;
    *(ushort4*)&L[(size_t)i * 4] = lv;
  }
}

// ---------------------------------------------------------------------------
// W[K][N] fp32 -> Th[N][K], Tl[N][K] bf16 (transpose + split). 64x64 tiles.
// ---------------------------------------------------------------------------
__global__ __launch_bounds__(256) void transpose_split(
    const float* __restrict__ W, ushort* __restrict__ Th,
    ushort* __restrict__ Tl, int K, int N) {
  __shared__ float t[64][65];
  const int k0 = blockIdx.y * 64, n0 = blockIdx.x * 64;
  const int c = threadIdx.x & 63, rg = threadIdx.x >> 6;
#pragma unroll
  for (int rr = 0; rr < 16; ++rr) {
    const int r = rg * 16 + rr;
    t[r][c] = W[(size_t)(k0 + r) * N + n0 + c];
  }
  __syncthreads();
#pragma unroll
  for (int rr = 0; rr < 16; ++rr) {
    const int n = rg * 16 + rr;
    const float x = t[c][n];
    ushort h16, l16;
    bsplit(x, h16, l16);
    const size_t o = (size_t)(n0 + n) * K + k0 + c;
    Th[o] = h16;
    Tl[o] = l16;
  }
}

// ---------------------------------------------------------------------------
// bf16x3 split MFMA GEMM: C = epi(A @ B^T + bias [+ res]); 128x128, BK=32.
// MODE 0: QKV -> bf16 outputs U0/U1/U2 (q_hi,k_hi,v_hi)
// MODE 1: Wo  (+res, fp32 C + hi/lo split out)
// MODE 2: W1  (erf-GELU, hi-only bf16 out, N=3072)
// MODE 3: W2  (+res, fp32 C; A single bf16)
// ---------------------------------------------------------------------------
template <int MODE, bool ASPLIT>
__global__ __launch_bounds__(256) void mfma_gemm(
    const ushort* __restrict__ Ah, const ushort* __restrict__ Al,
    const ushort* __restrict__ B0h, const ushort* __restrict__ B0l,
    const ushort* __restrict__ B1h, const ushort* __restrict__ B1l,
    const ushort* __restrict__ B2h, const ushort* __restrict__ B2l,
    const float* __restrict__ bias0, const float* __restrict__ bias1,
    const float* __restrict__ bias2, const float* __restrict__ res,
    float* __restrict__ C0, ushort* __restrict__ Chi,
    ushort* __restrict__ Clo, ushort* __restrict__ U0,
    ushort* __restrict__ U1, ushort* __restrict__ U2, int Kd) {
  constexpr int NARR = ASPLIT ? 4 : 3;  // 0=Ah 1=Bh 2=Bl [3=Al]
  __shared__ ushort lds[NARR][4096];    // 8 KB each

  const int tid = threadIdx.x;
  const int w = tid >> 6, l = tid & 63;
  const int wm = w >> 1, wn = w & 1;
  const int r16 = l & 15, kg = l >> 4;
  const int bn = blockIdx.x, bm = blockIdx.y;

  const ushort* Bh = B0h;
  const ushort* Bl = B0l;
  const float* bias = bias0;
  ushort* Uout = U0;
  int colBase = bn * 128, bRow0 = bn * 128;
  if (MODE == 0) {
    const int sel = bn / 6;
    Bh = sel == 0 ? B0h : sel == 1 ? B1h : B2h;
    Bl = sel == 0 ? B0l : sel == 1 ? B1l : B2l;
    bias = sel == 0 ? bias0 : sel == 1 ? bias1 : bias2;
    Uout = sel == 0 ? U0 : sel == 1 ? U1 : U2;
    colBase = (bn % 6) * 128;
    bRow0 = colBase;
  }
  const int aRow0 = bm * 128;
  const int N = (MODE == 2) ? Fn : Dn;

  f4acc acc[4][4] = {};

  for (int k0 = 0; k0 < Kd; k0 += 32) {
    __syncthreads();
#pragma unroll
    for (int ii = 0; ii < 2; ++ii) {
      const int row = ii * 64 + l;
      const size_t aoff = (size_t)(aRow0 + row) * Kd + k0 + w * 8;
      const size_t boff = (size_t)(bRow0 + row) * Kd + k0 + w * 8;
      const int ldsOff = (w * 128 + ii * 64) * 8;
      gload16(Ah + aoff, &lds[0][ldsOff]);
      gload16(Bh + boff, &lds[1][ldsOff]);
      gload16(Bl + boff, &lds[2][ldsOff]);
      if (ASPLIT) gload16(Al + aoff, &lds[NARR - 1][ldsOff]);
    }
    __syncthreads();

    bfrag ah[4], al[4], bh[4], bl[4];
#pragma unroll
    for (int m = 0; m < 4; ++m) {
      const int p = (kg * 128 + wm * 64 + m * 16 + r16) * 8;
      ah[m] = *(const bfrag*)&lds[0][p];
      if (ASPLIT) al[m] = *(const bfrag*)&lds[NARR - 1][p];
    }
#pragma unroll
    for (int n = 0; n < 4; ++n) {
      const int p = (kg * 128 + wn * 64 + n * 16 + r16) * 8;
      bh[n] = *(const bfrag*)&lds[1][p];
      bl[n] = *(const bfrag*)&lds[2][p];
    }
#pragma unroll
    for (int m = 0; m < 4; ++m)
#pragma unroll
      for (int n = 0; n < 4; ++n) {
        acc[m][n] = mfma16(ah[m], bh[n], acc[m][n]);
        acc[m][n] = mfma16(ah[m], bl[n], acc[m][n]);
        if (ASPLIT) acc[m][n] = mfma16(al[m], bh[n], acc[m][n]);
      }
  }

  float bc[4];
#pragma unroll
  for (int n = 0; n < 4; ++n) bc[n] = bias[colBase + wn * 64 + n * 16 + r16];

#pragma unroll
  for (int m = 0; m < 4; ++m)
#pragma unroll
    for (int e = 0; e < 4; ++e) {
      const int grow = aRow0 + wm * 64 + m * 16 + (l >> 4) * 4 + e;
#pragma unroll
      for (int n = 0; n < 4; ++n) {
        const int gcol = colBase + wn * 64 + n * 16 + r16;
        const size_t o = (size_t)grow * N + gcol;
        float v = acc[m][n][e] + bc[n];
        if (MODE == 0) {
          Uout[o] = rne_bf16(v);
        } else if (MODE == 1) {
          v += res[o];
          C0[o] = v;
          ushort h16, l16;
          bsplit(v, h16, l16);
          Chi[o] = h16;
          Clo[o] = l16;
        } else if (MODE == 2) {
          v = 0.5f * v * (1.f + erff(v * 0.70710678118654752f));
          Chi[o] = rne_bf16(v);
        } else {  // MODE 3
          v += res[o];
          C0[o] = v;
        }
      }
    }
}

// ---------------------------------------------------------------------------
// Flash-style MFMA attention. Block = (i-tile of 64 rows, b*12+h). 4 waves.
// Per j-tile (128): stage K/V bf16 (swizzled LDS), QK^T via MFMA, exp (no
// max-sub: scores bounded ~8; masked -> exp(-1e9)=0), P bf16 -> LDS, PV MFMA,
// write UNNORMALIZED exp to attn (attn_norm normalizes later), rowsums via
// shuffle, ctx scaled in epilogue.
// ---------------------------------------------------------------------------
__global__ __launch_bounds__(256, 2) void attn_kernel(
    const ushort* __restrict__ q_hi, const ushort* __restrict__ k_hi,
    const ushort* __restrict__ v_hi, const float* __restrict__ mask,
    const float* __restrict__ adjoin, float* __restrict__ attn,
    float* __restrict__ ctx, float* __restrict__ rowsums) {
  __shared__ __align__(16) char sm[58624];
  char* Qs = sm;                      // [64][64] bf16, swz128   (8 KB)
  char* Ks = sm + 8192;               // [128][64] bf16, swz128  (16 KB)
  char* Vs = sm + 24576;              // [128][64] bf16, swzV128 (16 KB)
  char* Ps = sm + 40960;              // [64][128] bf16, swz256  (16 KB)
  float* rsumLds = (float*)(sm + 57344);  // [4][64]
  float* rtot = (float*)(sm + 58368);     // [64]

  const int tid = threadIdx.x;
  const int w = tid >> 6, l = tid & 63;
  const int i0 = blockIdx.x * 64;
  const int bh = blockIdx.y;
  const int b = bh / Hn, h = bh % Hn;

  // ---- stage Q tile (once) ----
#pragma unroll
  for (int u = 0; u < 2; ++u) {
    const int qc = tid + 256 * u;
    const int r = qc >> 3, s = qc & 7;
    const uint4 val =
        *(const uint4*)(q_hi + (size_t)(b * Sn + i0 + r) * Dn + h * DHn + s * 8);
    *(uint4*)(Qs + swz128(r, s * 16)) = val;
  }

  f4acc acc_pv[4] = {};
  float rs[4][4];
#pragma unroll
  for (int m = 0; m < 4; ++m)
#pragma unroll
    for (int e = 0; e < 4; ++e) rs[m][e] = 0.f;

  const size_t attn_base = ((size_t)bh * Sn + i0) * Sn;

  for (int jt = 0; jt < 8; ++jt) {
    // ---- load K/V tile to regs (global, coalesced) ----
    uint4 kr[4], vr[4];
#pragma unroll
    for (int u = 0; u < 4; ++u) {
      const int qc = tid + 256 * u;
      const int r = qc >> 3, s = qc & 7;
      const size_t gOff =
          (size_t)(b * Sn + jt * 128 + r) * Dn + h * DHn + s * 8;
      kr[u] = *(const uint4*)(k_hi + gOff);
      vr[u] = *(const uint4*)(v_hi + gOff);
    }
    __syncthreads();  // prev jt consumers (PV/writeback) done
#pragma unroll
    for (int u = 0; u < 4; ++u) {
      const int qc = tid + 256 * u;
      const int r = qc >> 3, s = qc & 7;
      *(uint4*)(Ks + swz128(r, s * 16)) = kr[u];
      *(uint4*)(Vs + swzV128(r, s * 16)) = vr[u];
    }
    __syncthreads();  // tiles ready (Q too on first iter)

    // ---- QK^T: wave strip = 32 cols ----
    f4acc s[4][2] = {};
#pragma unroll
    for (int kk = 0; kk < 2; ++kk) {
      bfrag qa[4], kb2[2];
#pragma unroll
      for (int m = 0; m < 4; ++m)
        qa[m] = *(const bfrag*)(Qs + swz128(16 * m + (l & 15),
                                            kk * 64 + (l >> 4) * 16));
#pragma unroll
      for (int n = 0; n < 2; ++n)
        kb2[n] = *(const bfrag*)(Ks + swz128(32 * w + 16 * n + (l & 15),
                                             kk * 64 + (l >> 4) * 16));
#pragma unroll
      for (int m = 0; m < 4; ++m)
#pragma unroll
        for (int n = 0; n < 2; ++n)
          s[m][n] = mfma16(qa[m], kb2[n], s[m][n]);
    }

    // ---- mask/adjoin + exp + P write + rowsum ----
    float mk[2];
#pragma unroll
    for (int n = 0; n < 2; ++n)
      mk[n] = mask[b * Sn + jt * 128 + 32 * w + 16 * n + (l & 15)] * (-1e9f);

#pragma unroll
    for (int m = 0; m < 4; ++m)
#pragma unroll
      for (int e = 0; e < 4; ++e) {
        const int i = 16 * m + (l >> 4) * 4 + e;
        float rowAcc = 0.f;
#pragma unroll
        for (int n = 0; n < 2; ++n) {
          const int jl = 32 * w + 16 * n + (l & 15);
          const float adj =
              adjoin[(size_t)(b * Sn + i0 + i) * Sn + jt * 128 + jl];
          const float sv = s[m][n][e] * 0.125f + mk[n] + adj;
          const float ev = __expf(sv);
          *(ushort*)(Ps + swz256(i, jl * 2)) = rne_bf16(ev);
          rowAcc += ev;
        }
        rowAcc += __shfl_xor(rowAcc, 1);
        rowAcc += __shfl_xor(rowAcc, 2);
        rowAcc += __shfl_xor(rowAcc, 4);
        rowAcc += __shfl_xor(rowAcc, 8);
        rs[m][e] += rowAcc;
      }
    __syncthreads();  // P ready

    // ---- PV: wave owns d-strip [16w,16w+16) ----
#pragma unroll
    for (int kk = 0; kk < 4; ++kk) {
      bfrag pa[4], vbf;
#pragma unroll
      for (int m = 0; m < 4; ++m)
        pa[m] = *(const bfrag*)(Ps + swz256(16 * m + (l & 15),
                                            kk * 64 + (l >> 4) * 16));
#pragma unroll
      for (int e = 0; e < 8; ++e) {
        const int j = kk * 32 + (l >> 4) * 8 + e;
        vbf[e] = *(const short*)(Vs + swzV128(j, (16 * w + (l & 15)) * 2));
      }
#pragma unroll
      for (int m = 0; m < 4; ++m) acc_pv[m] = mfma16(pa[m], vbf, acc_pv[m]);
    }

    // ---- coalesced attn writeback (unnormalized exp, from P_lds) ----
    {
      const int r = tid >> 2, c = tid & 3;
      const size_t gbase = attn_base + (size_t)r * Sn + jt * 128 + c * 32;
#pragma unroll
      for (int uu = 0; uu < 4; ++uu) {
        const bfrag pb = *(const bfrag*)(Ps + swz256(r, c * 64 + uu * 16));
        float4 f0, f1;
        f0.x = bf2f((ushort)pb[0]); f0.y = bf2f((ushort)pb[1]);
        f0.z = bf2f((ushort)pb[2]); f0.w = bf2f((ushort)pb[3]);
        f1.x = bf2f((ushort)pb[4]); f1.y = bf2f((ushort)pb[5]);
        f1.z = bf2f((ushort)pb[6]); f1.w = bf2f((ushort)pb[7]);
        *(float4*)(attn + gbase + uu * 8) = f0;
        *(float4*)(attn + gbase + uu * 8 + 4) = f1;
      }
    }
  }

  // ---- rowsum cross-wave reduce + ctx epilogue ----
  if ((l & 15) == 0) {
#pragma unroll
    for (int m = 0; m < 4; ++m)
#pragma unroll
      for (int e = 0; e < 4; ++e)
        rsumLds[w * 64 + 16 * m + (l >> 4) * 4 + e] = rs[m][e];
  }
  __syncthreads();
  if (tid < 64) {
    const float tot = rsumLds[tid] + rsumLds[64 + tid] + rsumLds[128 + tid] +
                      rsumLds[192 + tid];
    rtot[tid] = tot;
    rowsums[(size_t)bh * Sn + i0 + tid] = tot;
  }
  __syncthreads();
#pragma unroll
  for (int m = 0; m < 4; ++m)
#pragma unroll
    for (int e = 0; e < 4; ++e) {
      const int i = 16 * m + (l >> 4) * 4 + e;
      const float inv = 1.0f / rtot[i];
      ctx[(size_t)(b * Sn + i0 + i) * Dn + h * DHn + 16 * w + (l & 15)] =
          acc_pv[m][e] * inv;
    }
}

// ---------------------------------------------------------------------------
// attn[row][:] *= 1/rowsums[row]; one block per row.
// ---------------------------------------------------------------------------
__global__ __launch_bounds__(256) void attn_norm(float* __restrict__ attn,
                                                 const float* __restrict__ rowsums) {
  const int row = blockIdx.x;
  const float inv = 1.0f / rowsums[row];
  float4* p = (float4*)(attn + (size_t)row * Sn) + threadIdx.x;
  float4 v = *p;
  v.x *= inv; v.y *= inv; v.z *= inv; v.w *= inv;
  *p = v;
}

// ---------------------------------------------------------------------------
// LayerNorm over last dim (768), one block per row.
// ---------------------------------------------------------------------------
__global__ __launch_bounds__(256) void ln_kernel(
    const float* __restrict__ xin, const float* __restrict__ gamma,
    const float* __restrict__ beta, float* __restrict__ out) {
  const int row = blockIdx.x;
  const float* xr = xin + (size_t)row * Dn;
  const int tid = threadIdx.x;
  const float v0 = xr[tid];
  const float v1 = xr[tid + 256];
  const float v2 = xr[tid + 512];
  float s = v0 + v1 + v2;
  float s2 = v0 * v0 + v1 * v1 + v2 * v2;
#pragma unroll
  for (int off = 32; off > 0; off >>= 1) {
    s += __shfl_xor(s, off);
    s2 += __shfl_xor(s2, off);
  }
  __shared__ float red[2][4];
  const int w = tid >> 6, l = tid & 63;
  if (l == 0) { red[0][w] = s; red[1][w] = s2; }
  __syncthreads();
  s = red[0][0] + red[0][1] + red[0][2] + red[0][3];
  s2 = red[1][0] + red[1][1] + red[1][2] + red[1][3];
  const float mu = s * (1.f / 768.f);
  const float var = s2 * (1.f / 768.f) - mu * mu;
  const float inv = 1.0f / sqrtf(var + 1e-6f);
  out[(size_t)row * Dn + tid] = (v0 - mu) * inv * gamma[tid] + beta[tid];
  out[(size_t)row * Dn + tid + 256] =
      (v1 - mu) * inv * gamma[tid + 256] + beta[tid + 256];
  out[(size_t)row * Dn + tid + 512] =
      (v2 - mu) * inv * gamma[tid + 512] + beta[tid + 512];
}

}  // namespace

extern "C" void kernel_launch(void* const* d_in, const int* in_sizes, int n_in,
                              void* d_out, int out_size, void* d_ws,
                              size_t ws_size, hipStream_t stream) {
  const float* x = (const float*)d_in[0];
  const float* mask = (const float*)d_in[2];
  const float* adjoin = (const float*)d_in[3];
  const float* Wq = (const float*)d_in[4];
  const float* bq = (const float*)d_in[5];
  const float* Wk = (const float*)d_in[6];
  const float* bk = (const float*)d_in[7];
  const float* Wv = (const float*)d_in[8];
  const float* bv = (const float*)d_in[9];
  const float* Wo = (const float*)d_in[10];
  const float* bo = (const float*)d_in[11];
  const float* W1 = (const float*)d_in[12];
  const float* b1 = (const float*)d_in[13];
  const float* W2 = (const float*)d_in[14];
  const float* b2 = (const float*)d_in[15];
  const float* gamma2 = (const float*)d_in[16];
  const float* beta2 = (const float*)d_in[17];

  float* out2 = (float*)d_out;               // [B,S,D]
  float* attn = out2 + (size_t)Mrows * Dn;   // [B,H,S,S]

  // ---- workspace layout (bytes); peak 115.6 MB (<= 125.9 proven) ----
  char* ws = (char*)d_ws;
  const size_t BFS = (size_t)Mrows * Dn * 2;   // 12,582,912 (bf16 token map)
  const size_t F32S = (size_t)Mrows * Dn * 4;  // 25,165,824
  ushort* q_hi = (ushort*)(ws);
  ushort* k_hi = (ushort*)(ws + BFS);
  ushort* v_hi = (ushort*)(ws + 2 * BFS);
  float* ctx = (float*)(ws + 3 * BFS);              // [37.7MB, 62.9MB)
  ushort* ctx_hi = (ushort*)(ws + 3 * BFS + F32S);  // [62.9, 75.5)
  ushort* ctx_lo = (ushort*)(ws + 4 * BFS + F32S);  // [75.5, 88.1)
  float* out1 = (float*)(ws + 5 * BFS + F32S);      // [88.1, 113.2)
  ushort* out1_hi = (ushort*)(ws);                  // over q_hi (dead)
  ushort* out1_lo = (ushort*)(ws + BFS);            // over k_hi (dead)
  ushort* h_hi = (ushort*)(ws + 2 * BFS);           // over v_hi+ctx+ctx_hi (50.3MB)
  const size_t WDD = (size_t)Dn * Dn * 2;           // 1.18 MB
  const size_t WDF = (size_t)Dn * Fn * 2;           // 4.72 MB
  char* wsW = ws + 5 * BFS + 2 * F32S;              // [113.2, 115.6)
  ushort* wot_hi = (ushort*)(wsW);
  ushort* wot_lo = (ushort*)(wsW + WDD);

  // ---- d_out scratch: out2 region dead until ln (step 8) ----
  char* o2r = (char*)out2;
  ushort* w1t_hi = (ushort*)(o2r);
  ushort* w1t_lo = (ushort*)(o2r + WDF);
  ushort* w2t_hi = (ushort*)(o2r + 2 * WDF);
  ushort* w2t_lo = (ushort*)(o2r + 3 * WDF);
  float* rowsums = (float*)(o2r + 4 * WDF);         // 393 KB, ends 19.3MB < 25.2

  // ---- d_out scratch: attn region dead until attn_kernel (step 3) ----
  char* scr = (char*)attn;
  ushort* x_hi = (ushort*)(scr);
  ushort* x_lo = (ushort*)(scr + BFS);
  ushort* wqt_hi = (ushort*)(scr + 2 * BFS);
  ushort* wqt_lo = (ushort*)(scr + 2 * BFS + WDD);
  ushort* wkt_hi = (ushort*)(scr + 2 * BFS + 2 * WDD);
  ushort* wkt_lo = (ushort*)(scr + 2 * BFS + 3 * WDD);
  ushort* wvt_hi = (ushort*)(scr + 2 * BFS + 4 * WDD);
  ushort* wvt_lo = (ushort*)(scr + 2 * BFS + 5 * WDD);

  const dim3 blk(256);

  // 1) input splits + weight transpose-splits
  split_rows<<<dim3(2048), blk, 0, stream>>>((const float4*)x, x_hi, x_lo,
                                             Mrows * Dn / 4);
  transpose_split<<<dim3(12, 12), blk, 0, stream>>>(Wq, wqt_hi, wqt_lo, Dn, Dn);
  transpose_split<<<dim3(12, 12), blk, 0, stream>>>(Wk, wkt_hi, wkt_lo, Dn, Dn);
  transpose_split<<<dim3(12, 12), blk, 0, stream>>>(Wv, wvt_hi, wvt_lo, Dn, Dn);
  transpose_split<<<dim3(12, 12), blk, 0, stream>>>(Wo, wot_hi, wot_lo, Dn, Dn);
  transpose_split<<<dim3(48, 12), blk, 0, stream>>>(W1, w1t_hi, w1t_lo, Dn, Fn);
  transpose_split<<<dim3(12, 48), blk, 0, stream>>>(W2, w2t_hi, w2t_lo, Fn, Dn);

  // 2) fused QKV projection -> bf16 q/k/v
  mfma_gemm<0, true><<<dim3(18, 64), blk, 0, stream>>>(
      x_hi, x_lo, wqt_hi, wqt_lo, wkt_hi, wkt_lo, wvt_hi, wvt_lo, bq, bk, bv,
      nullptr, nullptr, nullptr, nullptr, q_hi, k_hi, v_hi, Dn);

  // 3) flash attention (attn <- unnormalized exp; ctx normalized; rowsums)
  attn_kernel<<<dim3(Sn / 64, Bn * Hn), blk, 0, stream>>>(
      q_hi, k_hi, v_hi, mask, adjoin, attn, ctx, rowsums);

  // 3b) normalize attn output
  attn_norm<<<dim3(Bn * Hn * Sn), blk, 0, stream>>>(attn, rowsums);

  // 4) split ctx for Wo GEMM
  split_rows<<<dim3(2048), blk, 0, stream>>>((const float4*)ctx, ctx_hi, ctx_lo,
                                             Mrows * Dn / 4);

  // 5) out1 = x + ctx @ Wo + bo  (+ hi/lo split)
  mfma_gemm<1, true><<<dim3(6, 64), blk, 0, stream>>>(
      ctx_hi, ctx_lo, wot_hi, wot_lo, nullptr, nullptr, nullptr, nullptr, bo,
      nullptr, nullptr, x, out1, out1_hi, out1_lo, nullptr, nullptr, nullptr,
      Dn);

  // 6) h_hi = bf16(gelu(out1 @ W1 + b1))
  mfma_gemm<2, true><<<dim3(24, 64), blk, 0, stream>>>(
      out1_hi, out1_lo, w1t_hi, w1t_lo, nullptr, nullptr, nullptr, nullptr, b1,
      nullptr, nullptr, nullptr, nullptr, h_hi, nullptr, nullptr, nullptr,
      nullptr, Dn);

  // 7) out1 += h @ W2 + b2 (in place; A single-bf16)
  mfma_gemm<3, false><<<dim3(6, 64), blk, 0, stream>>>(
      h_hi, nullptr, w2t_hi, w2t_lo, nullptr, nullptr, nullptr, nullptr, b2,
      nullptr, nullptr, out1, out1, nullptr, nullptr, nullptr, nullptr,
      nullptr, Fn);

  // 8) out2 = layernorm(out1)
  ln_kernel<<<dim3(Mrows), blk, 0, stream>>>(out1, gamma2, beta2, out2);
}

// Round 5
// 1228.550 us; speedup vs baseline: 2.7650x; 1.0142x over previous
//
#include <hip/hip_runtime.h>
#include <math.h>

namespace {

constexpr int Bn = 8, Sn = 1024, Dn = 768, Hn = 12, DHn = 64, Fn = 3072;
constexpr int Mrows = Bn * Sn;  // 8192 token rows

typedef __attribute__((ext_vector_type(8))) short bfrag;   // 8 bf16 = 4 VGPR
typedef __attribute__((ext_vector_type(4))) float f4acc;   // 4 f32 acc

typedef const __attribute__((address_space(1))) unsigned int* gas_t;
typedef __attribute__((address_space(3))) unsigned int* las_t;

__device__ __forceinline__ void gload16(const ushort* g, ushort* l) {
  __builtin_amdgcn_global_load_lds((gas_t)g, (las_t)l, 16, 0, 0);
}

__device__ __forceinline__ f4acc mfma16(bfrag a, bfrag b, f4acc c) {
  return __builtin_amdgcn_mfma_f32_16x16x32_bf16(a, b, c, 0, 0, 0);
}

// split fp32 -> bf16 hi + bf16 lo (truncation; residual ~2^-16 rel)
__device__ __forceinline__ void bsplit(float x, ushort& h, ushort& l) {
  union { float f; unsigned u; } a; a.f = x;
  const ushort hi = (ushort)(a.u >> 16);
  union { unsigned u; float f; } hf; hf.u = (unsigned)hi << 16;
  union { float f; unsigned u; } b; b.f = x - hf.f;
  h = hi; l = (ushort)(b.u >> 16);
}

__device__ __forceinline__ ushort rne_bf16(float x) {
  union { float f; unsigned u; } a; a.f = x;
  const unsigned r = a.u + 0x7FFF + ((a.u >> 16) & 1);
  return (ushort)(r >> 16);
}

__device__ __forceinline__ float bf2f(ushort x) {
  union { unsigned u; float f; } t; t.u = ((unsigned)x) << 16;
  return t.f;
}

// LDS XOR swizzles for 128B rows (write-side and read-side must match)
__device__ __forceinline__ int swz128(int row, int byteInRow) {
  return row * 128 + (byteInRow ^ ((row & 7) << 4));
}
__device__ __forceinline__ int swzV128(int row, int byteInRow) { // key=(row>>3)&7
  return row * 128 + (byteInRow ^ (((row >> 3) & 7) << 4));
}

// ---------------------------------------------------------------------------
// Elementwise fp32 -> (hi, lo) bf16 split, vectorized.
// ---------------------------------------------------------------------------
__global__ __launch_bounds__(256) void split_rows(const float4* __restrict__ X,
                                                  ushort* __restrict__ H,
                                                  ushort* __restrict__ L,
                                                  int n4) {
  int i = blockIdx.x * 256 + threadIdx.x;
  const int stride = gridDim.x * 256;
  for (; i < n4; i += stride) {
    const float4 v = X[i];
    ushort h0, l0, h1, l1, h2, l2, h3, l3;
    bsplit(v.x, h0, l0); bsplit(v.y, h1, l1);
    bsplit(v.z, h2, l2); bsplit(v.w, h3, l3);
    ushort4 hv; hv.x = h0; hv.y = h1; hv.z = h2; hv.w = h3;
    ushort4 lv; lv.x = l0; lv.y = l1; lv.z = l2; lv.w = l3;
    *(ushort4*)&H[(size_t)i * 4] = hv;
    *(ushort4*)&L[(size_t)i * 4] = lv;
  }
}

// ---------------------------------------------------------------------------
// W[K][N] fp32 -> Th[N][K], Tl[N][K] bf16 (transpose + split). 64x64 tiles.
// ---------------------------------------------------------------------------
__global__ __launch_bounds__(256) void transpose_split(
    const float* __restrict__ W, ushort* __restrict__ Th,
    ushort* __restrict__ Tl, int K, int N) {
  __shared__ float t[64][65];
  const int k0 = blockIdx.y * 64, n0 = blockIdx.x * 64;
  const int c = threadIdx.x & 63, rg = threadIdx.x >> 6;
#pragma unroll
  for (int rr = 0; rr < 16; ++rr) {
    const int r = rg * 16 + rr;
    t[r][c] = W[(size_t)(k0 + r) * N + n0 + c];
  }
  __syncthreads();
#pragma unroll
  for (int rr = 0; rr < 16; ++rr) {
    const int n = rg * 16 + rr;
    const float x = t[c][n];
    ushort h16, l16;
    bsplit(x, h16, l16);
    const size_t o = (size_t)(n0 + n) * K + k0 + c;
    Th[o] = h16;
    Tl[o] = l16;
  }
}

// ---------------------------------------------------------------------------
// bf16x3 split MFMA GEMM: C = epi(A @ B^T + bias [+ res]); 128x128, BK=32.
// MODE 0: QKV -> bf16 outputs U0/U1/U2 (q_hi,k_hi,v_hi)
// MODE 1: Wo  (+res, fp32 C + hi/lo split out)
// MODE 2: W1  (erf-GELU, hi-only bf16 out, N=3072)
// MODE 3: W2  (+res, fp32 C; A single bf16)
// ---------------------------------------------------------------------------
template <int MODE, bool ASPLIT>
__global__ __launch_bounds__(256) void mfma_gemm(
    const ushort* __restrict__ Ah, const ushort* __restrict__ Al,
    const ushort* __restrict__ B0h, const ushort* __restrict__ B0l,
    const ushort* __restrict__ B1h, const ushort* __restrict__ B1l,
    const ushort* __restrict__ B2h, const ushort* __restrict__ B2l,
    const float* __restrict__ bias0, const float* __restrict__ bias1,
    const float* __restrict__ bias2, const float* __restrict__ res,
    float* __restrict__ C0, ushort* __restrict__ Chi,
    ushort* __restrict__ Clo, ushort* __restrict__ U0,
    ushort* __restrict__ U1, ushort* __restrict__ U2, int Kd) {
  constexpr int NARR = ASPLIT ? 4 : 3;  // 0=Ah 1=Bh 2=Bl [3=Al]
  __shared__ ushort lds[NARR][4096];    // 8 KB each

  const int tid = threadIdx.x;
  const int w = tid >> 6, l = tid & 63;
  const int wm = w >> 1, wn = w & 1;
  const int r16 = l & 15, kg = l >> 4;
  const int bn = blockIdx.x, bm = blockIdx.y;

  const ushort* Bh = B0h;
  const ushort* Bl = B0l;
  const float* bias = bias0;
  ushort* Uout = U0;
  int colBase = bn * 128, bRow0 = bn * 128;
  if (MODE == 0) {
    const int sel = bn / 6;
    Bh = sel == 0 ? B0h : sel == 1 ? B1h : B2h;
    Bl = sel == 0 ? B0l : sel == 1 ? B1l : B2l;
    bias = sel == 0 ? bias0 : sel == 1 ? bias1 : bias2;
    Uout = sel == 0 ? U0 : sel == 1 ? U1 : U2;
    colBase = (bn % 6) * 128;
    bRow0 = colBase;
  }
  const int aRow0 = bm * 128;
  const int N = (MODE == 2) ? Fn : Dn;

  f4acc acc[4][4] = {};

  for (int k0 = 0; k0 < Kd; k0 += 32) {
    __syncthreads();
#pragma unroll
    for (int ii = 0; ii < 2; ++ii) {
      const int row = ii * 64 + l;
      const size_t aoff = (size_t)(aRow0 + row) * Kd + k0 + w * 8;
      const size_t boff = (size_t)(bRow0 + row) * Kd + k0 + w * 8;
      const int ldsOff = (w * 128 + ii * 64) * 8;
      gload16(Ah + aoff, &lds[0][ldsOff]);
      gload16(Bh + boff, &lds[1][ldsOff]);
      gload16(Bl + boff, &lds[2][ldsOff]);
      if (ASPLIT) gload16(Al + aoff, &lds[NARR - 1][ldsOff]);
    }
    __syncthreads();

    bfrag ah[4], al[4], bh[4], bl[4];
#pragma unroll
    for (int m = 0; m < 4; ++m) {
      const int p = (kg * 128 + wm * 64 + m * 16 + r16) * 8;
      ah[m] = *(const bfrag*)&lds[0][p];
      if (ASPLIT) al[m] = *(const bfrag*)&lds[NARR - 1][p];
    }
#pragma unroll
    for (int n = 0; n < 4; ++n) {
      const int p = (kg * 128 + wn * 64 + n * 16 + r16) * 8;
      bh[n] = *(const bfrag*)&lds[1][p];
      bl[n] = *(const bfrag*)&lds[2][p];
    }
#pragma unroll
    for (int m = 0; m < 4; ++m)
#pragma unroll
      for (int n = 0; n < 4; ++n) {
        acc[m][n] = mfma16(ah[m], bh[n], acc[m][n]);
        acc[m][n] = mfma16(ah[m], bl[n], acc[m][n]);
        if (ASPLIT) acc[m][n] = mfma16(al[m], bh[n], acc[m][n]);
      }
  }

  float bc[4];
#pragma unroll
  for (int n = 0; n < 4; ++n) bc[n] = bias[colBase + wn * 64 + n * 16 + r16];

#pragma unroll
  for (int m = 0; m < 4; ++m)
#pragma unroll
    for (int e = 0; e < 4; ++e) {
      const int grow = aRow0 + wm * 64 + m * 16 + (l >> 4) * 4 + e;
#pragma unroll
      for (int n = 0; n < 4; ++n) {
        const int gcol = colBase + wn * 64 + n * 16 + r16;
        const size_t o = (size_t)grow * N + gcol;
        float v = acc[m][n][e] + bc[n];
        if (MODE == 0) {
          Uout[o] = rne_bf16(v);
        } else if (MODE == 1) {
          v += res[o];
          C0[o] = v;
          ushort h16, l16;
          bsplit(v, h16, l16);
          Chi[o] = h16;
          Clo[o] = l16;
        } else if (MODE == 2) {
          v = 0.5f * v * (1.f + erff(v * 0.70710678118654752f));
          Chi[o] = rne_bf16(v);
        } else {  // MODE 3
          v += res[o];
          C0[o] = v;
        }
      }
    }
}

// ---------------------------------------------------------------------------
// Flash-style MFMA attention v2. Block = (i-tile of 64 rows, b*12+h). 4 waves.
// JBLK=64; 16 j-tiles. Q in registers. Per j-tile: reg-stage K/V (bf16,
// swizzled LDS) + adjoin (f32, padded LDS, coalesced float4), QK^T MFMA,
// exp (no max-sub; masked -> exp(-1e9)=0) reading adjoin from LDS, P bf16 ->
// swizzled LDS, PV MFMA, coalesced UNNORMALIZED attn writeback. rowsums via
// shuffle+LDS; ctx normalized in epilogue; attn_norm normalizes attn later.
// ---------------------------------------------------------------------------
__global__ __launch_bounds__(256, 3) void attn_kernel(
    const ushort* __restrict__ q_hi, const ushort* __restrict__ k_hi,
    const ushort* __restrict__ v_hi, const float* __restrict__ mask,
    const float* __restrict__ adjoin, float* __restrict__ attn,
    float* __restrict__ ctx, float* __restrict__ rowsums) {
  __shared__ __align__(16) char sm[43520];
  char* Ks = sm;                          // [64][64] bf16, swz128  (8 KB)
  char* Vs = sm + 8192;                   // [64][64] bf16, swzV128 (8 KB)
  char* Ps = sm + 16384;                  // [64][64] bf16, swz128  (8 KB)
  float* AdjS = (float*)(sm + 24576);     // [64][68] f32 padded    (17 KB)
  float* rsumLds = (float*)(sm + 41984);  // [4][64]
  float* rtot = (float*)(sm + 43008);     // [64]

  const int tid = threadIdx.x;
  const int w = tid >> 6, l = tid & 63;
  const int i0 = blockIdx.x * 64;
  const int bh = blockIdx.y;
  const int b = bh / Hn, h = bh % Hn;
  const int l4 = l & 15, lg = l >> 4;

  // ---- Q tile in registers: qa[kk][m] = A-frag rows 16m+(l&15), k kk*32.. ----
  bfrag qa[2][4];
#pragma unroll
  for (int kk = 0; kk < 2; ++kk)
#pragma unroll
    for (int m = 0; m < 4; ++m)
      qa[kk][m] = *(const bfrag*)(q_hi +
          (size_t)(b * Sn + i0 + 16 * m + l4) * Dn + h * DHn + kk * 32 + lg * 8);

  f4acc acc_pv[4] = {};
  float rs[4][4];
#pragma unroll
  for (int m = 0; m < 4; ++m)
#pragma unroll
    for (int e = 0; e < 4; ++e) rs[m][e] = 0.f;

  const size_t attn_base = ((size_t)bh * Sn + i0) * Sn;
  const int stg_r = tid >> 3, stg_s = tid & 7;     // K/V staging map
  const int adj_r = tid >> 4, adj_f = tid & 15;    // adjoin staging map

  for (int jt = 0; jt < 16; ++jt) {
    const int j0 = jt * 64;
    // ---- issue global loads into regs (coalesced) ----
    uint4 kr[2], vr[2];
    float4 ar[4];
#pragma unroll
    for (int u = 0; u < 2; ++u) {
      const int r = stg_r + 32 * u;
      const size_t gOff = (size_t)(b * Sn + j0 + r) * Dn + h * DHn + stg_s * 8;
      kr[u] = *(const uint4*)(k_hi + gOff);
      vr[u] = *(const uint4*)(v_hi + gOff);
    }
#pragma unroll
    for (int u = 0; u < 4; ++u) {
      const int r = adj_r + 16 * u;
      ar[u] = *(const float4*)(adjoin + (size_t)(b * Sn + i0 + r) * Sn + j0 +
                               adj_f * 4);
    }
    const float mval = mask[b * Sn + j0 + 16 * w + l4] * (-1e9f);

    __syncthreads();  // prev jt consumers done
#pragma unroll
    for (int u = 0; u < 2; ++u) {
      const int r = stg_r + 32 * u;
      *(uint4*)(Ks + swz128(r, stg_s * 16)) = kr[u];
      *(uint4*)(Vs + swzV128(r, stg_s * 16)) = vr[u];
    }
#pragma unroll
    for (int u = 0; u < 4; ++u) {
      const int r = adj_r + 16 * u;
      *(float4*)(AdjS + r * 68 + adj_f * 4) = ar[u];
    }
    __syncthreads();  // tiles ready

    // ---- QK^T: wave w owns cols [16w, 16w+16) ----
    f4acc s[4] = {};
#pragma unroll
    for (int kk = 0; kk < 2; ++kk) {
      bfrag kb2 = *(const bfrag*)(Ks + swz128(16 * w + l4, kk * 64 + lg * 16));
#pragma unroll
      for (int m = 0; m < 4; ++m) s[m] = mfma16(qa[kk][m], kb2, s[m]);
    }

    // ---- exp + P write + rowsum (adjoin from LDS) ----
    const int jl = 16 * w + l4;
#pragma unroll
    for (int m = 0; m < 4; ++m)
#pragma unroll
      for (int e = 0; e < 4; ++e) {
        const int i = 16 * m + lg * 4 + e;
        const float adj = AdjS[i * 68 + jl];
        const float sv = s[m][e] * 0.125f + mval + adj;
        const float ev = __expf(sv);
        *(ushort*)(Ps + swz128(i, jl * 2)) = rne_bf16(ev);
        float rowAcc = ev;
        rowAcc += __shfl_xor(rowAcc, 1);
        rowAcc += __shfl_xor(rowAcc, 2);
        rowAcc += __shfl_xor(rowAcc, 4);
        rowAcc += __shfl_xor(rowAcc, 8);
        rs[m][e] += rowAcc;
      }
    __syncthreads();  // P ready

    // ---- PV: wave owns d-strip [16w,16w+16) ----
#pragma unroll
    for (int kk = 0; kk < 2; ++kk) {
      bfrag pa[4], vbf;
#pragma unroll
      for (int m = 0; m < 4; ++m)
        pa[m] = *(const bfrag*)(Ps + swz128(16 * m + l4, kk * 64 + lg * 16));
#pragma unroll
      for (int e = 0; e < 8; ++e) {
        const int j = kk * 32 + lg * 8 + e;
        vbf[e] = *(const short*)(Vs + swzV128(j, (16 * w + l4) * 2));
      }
#pragma unroll
      for (int m = 0; m < 4; ++m) acc_pv[m] = mfma16(pa[m], vbf, acc_pv[m]);
    }

    // ---- coalesced attn writeback (unnormalized exp, from Ps) ----
    {
      const int r = tid >> 2, c = tid & 3;
      const bfrag p0 = *(const bfrag*)(Ps + swz128(r, c * 32));
      const bfrag p1 = *(const bfrag*)(Ps + swz128(r, c * 32 + 16));
      float4 f0, f1, f2, f3;
      f0.x = bf2f((ushort)p0[0]); f0.y = bf2f((ushort)p0[1]);
      f0.z = bf2f((ushort)p0[2]); f0.w = bf2f((ushort)p0[3]);
      f1.x = bf2f((ushort)p0[4]); f1.y = bf2f((ushort)p0[5]);
      f1.z = bf2f((ushort)p0[6]); f1.w = bf2f((ushort)p0[7]);
      f2.x = bf2f((ushort)p1[0]); f2.y = bf2f((ushort)p1[1]);
      f2.z = bf2f((ushort)p1[2]); f2.w = bf2f((ushort)p1[3]);
      f3.x = bf2f((ushort)p1[4]); f3.y = bf2f((ushort)p1[5]);
      f3.z = bf2f((ushort)p1[6]); f3.w = bf2f((ushort)p1[7]);
      const size_t gbase = attn_base + (size_t)r * Sn + j0 + c * 16;
      *(float4*)(attn + gbase) = f0;
      *(float4*)(attn + gbase + 4) = f1;
      *(float4*)(attn + gbase + 8) = f2;
      *(float4*)(attn + gbase + 12) = f3;
    }
  }

  // ---- rowsum cross-wave reduce + ctx epilogue ----
  if (l4 == 0) {
#pragma unroll
    for (int m = 0; m < 4; ++m)
#pragma unroll
      for (int e = 0; e < 4; ++e)
        rsumLds[w * 64 + 16 * m + lg * 4 + e] = rs[m][e];
  }
  __syncthreads();
  if (tid < 64) {
    const float tot = rsumLds[tid] + rsumLds[64 + tid] + rsumLds[128 + tid] +
                      rsumLds[192 + tid];
    rtot[tid] = tot;
    rowsums[(size_t)bh * Sn + i0 + tid] = tot;
  }
  __syncthreads();
#pragma unroll
  for (int m = 0; m < 4; ++m)
#pragma unroll
    for (int e = 0; e < 4; ++e) {
      const int i = 16 * m + lg * 4 + e;
      const float inv = 1.0f / rtot[i];
      ctx[(size_t)(b * Sn + i0 + i) * Dn + h * DHn + 16 * w + l4] =
          acc_pv[m][e] * inv;
    }
}

// ---------------------------------------------------------------------------
// attn[row][:] *= 1/rowsums[row]; one block per row.
// ---------------------------------------------------------------------------
__global__ __launch_bounds__(256) void attn_norm(float* __restrict__ attn,
                                                 const float* __restrict__ rowsums) {
  const int row = blockIdx.x;
  const float inv = 1.0f / rowsums[row];
  float4* p = (float4*)(attn + (size_t)row * Sn) + threadIdx.x;
  float4 v = *p;
  v.x *= inv; v.y *= inv; v.z *= inv; v.w *= inv;
  *p = v;
}

// ---------------------------------------------------------------------------
// LayerNorm over last dim (768), one block per row.
// ---------------------------------------------------------------------------
__global__ __launch_bounds__(256) void ln_kernel(
    const float* __restrict__ xin, const float* __restrict__ gamma,
    const float* __restrict__ beta, float* __restrict__ out) {
  const int row = blockIdx.x;
  const float* xr = xin + (size_t)row * Dn;
  const int tid = threadIdx.x;
  const float v0 = xr[tid];
  const float v1 = xr[tid + 256];
  const float v2 = xr[tid + 512];
  float s = v0 + v1 + v2;
  float s2 = v0 * v0 + v1 * v1 + v2 * v2;
#pragma unroll
  for (int off = 32; off > 0; off >>= 1) {
    s += __shfl_xor(s, off);
    s2 += __shfl_xor(s2, off);
  }
  __shared__ float red[2][4];
  const int w = tid >> 6, l = tid & 63;
  if (l == 0) { red[0][w] = s; red[1][w] = s2; }
  __syncthreads();
  s = red[0][0] + red[0][1] + red[0][2] + red[0][3];
  s2 = red[1][0] + red[1][1] + red[1][2] + red[1][3];
  const float mu = s * (1.f / 768.f);
  const float var = s2 * (1.f / 768.f) - mu * mu;
  const float inv = 1.0f / sqrtf(var + 1e-6f);
  out[(size_t)row * Dn + tid] = (v0 - mu) * inv * gamma[tid] + beta[tid];
  out[(size_t)row * Dn + tid + 256] =
      (v1 - mu) * inv * gamma[tid + 256] + beta[tid + 256];
  out[(size_t)row * Dn + tid + 512] =
      (v2 - mu) * inv * gamma[tid + 512] + beta[tid + 512];
}

}  // namespace

extern "C" void kernel_launch(void* const* d_in, const int* in_sizes, int n_in,
                              void* d_out, int out_size, void* d_ws,
                              size_t ws_size, hipStream_t stream) {
  const float* x = (const float*)d_in[0];
  const float* mask = (const float*)d_in[2];
  const float* adjoin = (const float*)d_in[3];
  const float* Wq = (const float*)d_in[4];
  const float* bq = (const float*)d_in[5];
  const float* Wk = (const float*)d_in[6];
  const float* bk = (const float*)d_in[7];
  const float* Wv = (const float*)d_in[8];
  const float* bv = (const float*)d_in[9];
  const float* Wo = (const float*)d_in[10];
  const float* bo = (const float*)d_in[11];
  const float* W1 = (const float*)d_in[12];
  const float* b1 = (const float*)d_in[13];
  const float* W2 = (const float*)d_in[14];
  const float* b2 = (const float*)d_in[15];
  const float* gamma2 = (const float*)d_in[16];
  const float* beta2 = (const float*)d_in[17];

  float* out2 = (float*)d_out;               // [B,S,D]
  float* attn = out2 + (size_t)Mrows * Dn;   // [B,H,S,S]

  // ---- workspace layout (bytes); peak 115.6 MB ----
  char* ws = (char*)d_ws;
  const size_t BFS = (size_t)Mrows * Dn * 2;   // 12,582,912 (bf16 token map)
  const size_t F32S = (size_t)Mrows * Dn * 4;  // 25,165,824
  ushort* q_hi = (ushort*)(ws);
  ushort* k_hi = (ushort*)(ws + BFS);
  ushort* v_hi = (ushort*)(ws + 2 * BFS);
  float* ctx = (float*)(ws + 3 * BFS);
  ushort* ctx_hi = (ushort*)(ws + 3 * BFS + F32S);
  ushort* ctx_lo = (ushort*)(ws + 4 * BFS + F32S);
  float* out1 = (float*)(ws + 5 * BFS + F32S);
  ushort* out1_hi = (ushort*)(ws);                  // over q_hi (dead)
  ushort* out1_lo = (ushort*)(ws + BFS);            // over k_hi (dead)
  ushort* h_hi = (ushort*)(ws + 2 * BFS);           // over v_hi+ctx+ctx_hi
  const size_t WDD = (size_t)Dn * Dn * 2;           // 1.18 MB
  const size_t WDF = (size_t)Dn * Fn * 2;           // 4.72 MB
  char* wsW = ws + 5 * BFS + 2 * F32S;
  ushort* wot_hi = (ushort*)(wsW);
  ushort* wot_lo = (ushort*)(wsW + WDD);

  // ---- d_out scratch: out2 region dead until ln (step 8) ----
  char* o2r = (char*)out2;
  ushort* w1t_hi = (ushort*)(o2r);
  ushort* w1t_lo = (ushort*)(o2r + WDF);
  ushort* w2t_hi = (ushort*)(o2r + 2 * WDF);
  ushort* w2t_lo = (ushort*)(o2r + 3 * WDF);
  float* rowsums = (float*)(o2r + 4 * WDF);

  // ---- d_out scratch: attn region dead until attn_kernel (step 3) ----
  char* scr = (char*)attn;
  ushort* x_hi = (ushort*)(scr);
  ushort* x_lo = (ushort*)(scr + BFS);
  ushort* wqt_hi = (ushort*)(scr + 2 * BFS);
  ushort* wqt_lo = (ushort*)(scr + 2 * BFS + WDD);
  ushort* wkt_hi = (ushort*)(scr + 2 * BFS + 2 * WDD);
  ushort* wkt_lo = (ushort*)(scr + 2 * BFS + 3 * WDD);
  ushort* wvt_hi = (ushort*)(scr + 2 * BFS + 4 * WDD);
  ushort* wvt_lo = (ushort*)(scr + 2 * BFS + 5 * WDD);

  const dim3 blk(256);

  // 1) input splits + weight transpose-splits
  split_rows<<<dim3(2048), blk, 0, stream>>>((const float4*)x, x_hi, x_lo,
                                             Mrows * Dn / 4);
  transpose_split<<<dim3(12, 12), blk, 0, stream>>>(Wq, wqt_hi, wqt_lo, Dn, Dn);
  transpose_split<<<dim3(12, 12), blk, 0, stream>>>(Wk, wkt_hi, wkt_lo, Dn, Dn);
  transpose_split<<<dim3(12, 12), blk, 0, stream>>>(Wv, wvt_hi, wvt_lo, Dn, Dn);
  transpose_split<<<dim3(12, 12), blk, 0, stream>>>(Wo, wot_hi, wot_lo, Dn, Dn);
  transpose_split<<<dim3(48, 12), blk, 0, stream>>>(W1, w1t_hi, w1t_lo, Dn, Fn);
  transpose_split<<<dim3(12, 48), blk, 0, stream>>>(W2, w2t_hi, w2t_lo, Fn, Dn);

  // 2) fused QKV projection -> bf16 q/k/v
  mfma_gemm<0, true><<<dim3(18, 64), blk, 0, stream>>>(
      x_hi, x_lo, wqt_hi, wqt_lo, wkt_hi, wkt_lo, wvt_hi, wvt_lo, bq, bk, bv,
      nullptr, nullptr, nullptr, nullptr, q_hi, k_hi, v_hi, Dn);

  // 3) flash attention (attn <- unnormalized exp; ctx normalized; rowsums)
  attn_kernel<<<dim3(Sn / 64, Bn * Hn), blk, 0, stream>>>(
      q_hi, k_hi, v_hi, mask, adjoin, attn, ctx, rowsums);

  // 3b) normalize attn output
  attn_norm<<<dim3(Bn * Hn * Sn), blk, 0, stream>>>(attn, rowsums);

  // 4) split ctx for Wo GEMM
  split_rows<<<dim3(2048), blk, 0, stream>>>((const float4*)ctx, ctx_hi, ctx_lo,
                                             Mrows * Dn / 4);

  // 5) out1 = x + ctx @ Wo + bo  (+ hi/lo split)
  mfma_gemm<1, true><<<dim3(6, 64), blk, 0, stream>>>(
      ctx_hi, ctx_lo, wot_hi, wot_lo, nullptr, nullptr, nullptr, nullptr, bo,
      nullptr, nullptr, x, out1, out1_hi, out1_lo, nullptr, nullptr, nullptr,
      Dn);

  // 6) h_hi = bf16(gelu(out1 @ W1 + b1))
  mfma_gemm<2, true><<<dim3(24, 64), blk, 0, stream>>>(
      out1_hi, out1_lo, w1t_hi, w1t_lo, nullptr, nullptr, nullptr, nullptr, b1,
      nullptr, nullptr, nullptr, nullptr, h_hi, nullptr, nullptr, nullptr,
      nullptr, Dn);

  // 7) out1 += h @ W2 + b2 (in place; A single-bf16)
  mfma_gemm<3, false><<<dim3(6, 64), blk, 0, stream>>>(
      h_hi, nullptr, w2t_hi, w2t_lo, nullptr, nullptr, nullptr, nullptr, b2,
      nullptr, nullptr, out1, out1, nullptr, nullptr, nullptr, nullptr,
      nullptr, Fn);

  // 8) out2 = layernorm(out1)
  ln_kernel<<<dim3(Mrows), blk, 0, stream>>>(out1, gamma2, beta2, out2);
}

// Round 7
// 1106.874 us; speedup vs baseline: 3.0689x; 1.1099x over previous
//
#include <hip/hip_runtime.h>
#include <math.h>

namespace {

constexpr int Bn = 8, Sn = 1024, Dn = 768, Hn = 12, DHn = 64, Fn = 3072;
constexpr int Mrows = Bn * Sn;  // 8192 token rows

typedef __attribute__((ext_vector_type(8))) short bfrag;   // 8 bf16 = 4 VGPR
typedef __attribute__((ext_vector_type(4))) float f4acc;   // 4 f32 acc
typedef __attribute__((ext_vector_type(4))) float f4v;     // native float4

typedef const __attribute__((address_space(1))) unsigned int* gas_t;
typedef __attribute__((address_space(3))) unsigned int* las_t;

__device__ __forceinline__ void gload16(const ushort* g, ushort* l) {
  __builtin_amdgcn_global_load_lds((gas_t)g, (las_t)l, 16, 0, 0);
}

__device__ __forceinline__ f4acc mfma16(bfrag a, bfrag b, f4acc c) {
  return __builtin_amdgcn_mfma_f32_16x16x32_bf16(a, b, c, 0, 0, 0);
}

// split fp32 -> bf16 hi + bf16 lo (truncation; residual ~2^-16 rel)
__device__ __forceinline__ void bsplit(float x, ushort& h, ushort& l) {
  union { float f; unsigned u; } a; a.f = x;
  const ushort hi = (ushort)(a.u >> 16);
  union { unsigned u; float f; } hf; hf.u = (unsigned)hi << 16;
  union { float f; unsigned u; } b; b.f = x - hf.f;
  h = hi; l = (ushort)(b.u >> 16);
}

__device__ __forceinline__ ushort rne_bf16(float x) {
  union { float f; unsigned u; } a; a.f = x;
  const unsigned r = a.u + 0x7FFF + ((a.u >> 16) & 1);
  return (ushort)(r >> 16);
}

__device__ __forceinline__ float bf2f(ushort x) {
  union { unsigned u; float f; } t; t.u = ((unsigned)x) << 16;
  return t.f;
}

// LDS XOR swizzles for 128B rows (write-side and read-side must match)
__device__ __forceinline__ int swz128(int row, int byteInRow) {
  return row * 128 + (byteInRow ^ ((row & 7) << 4));
}
__device__ __forceinline__ int swzV128(int row, int byteInRow) { // key=(row>>3)&7
  return row * 128 + (byteInRow ^ (((row >> 3) & 7) << 4));
}

// ---------------------------------------------------------------------------
// Elementwise fp32 -> (hi, lo) bf16 split, vectorized.
// ---------------------------------------------------------------------------
__global__ __launch_bounds__(256) void split_rows(const float4* __restrict__ X,
                                                  ushort* __restrict__ H,
                                                  ushort* __restrict__ L,
                                                  int n4) {
  int i = blockIdx.x * 256 + threadIdx.x;
  const int stride = gridDim.x * 256;
  for (; i < n4; i += stride) {
    const float4 v = X[i];
    ushort h0, l0, h1, l1, h2, l2, h3, l3;
    bsplit(v.x, h0, l0); bsplit(v.y, h1, l1);
    bsplit(v.z, h2, l2); bsplit(v.w, h3, l3);
    ushort4 hv; hv.x = h0; hv.y = h1; hv.z = h2; hv.w = h3;
    ushort4 lv; lv.x = l0; lv.y = l1; lv.z = l2; lv.w = l3;
    *(ushort4*)&H[(size_t)i * 4] = hv;
    *(ushort4*)&L[(size_t)i * 4] = lv;
  }
}

// ---------------------------------------------------------------------------
// W[K][N] fp32 -> Th[N][K], Tl[N][K] bf16 (transpose + split). 64x64 tiles.
// ---------------------------------------------------------------------------
__global__ __launch_bounds__(256) void transpose_split(
    const float* __restrict__ W, ushort* __restrict__ Th,
    ushort* __restrict__ Tl, int K, int N) {
  __shared__ float t[64][65];
  const int k0 = blockIdx.y * 64, n0 = blockIdx.x * 64;
  const int c = threadIdx.x & 63, rg = threadIdx.x >> 6;
#pragma unroll
  for (int rr = 0; rr < 16; ++rr) {
    const int r = rg * 16 + rr;
    t[r][c] = W[(size_t)(k0 + r) * N + n0 + c];
  }
  __syncthreads();
#pragma unroll
  for (int rr = 0; rr < 16; ++rr) {
    const int n = rg * 16 + rr;
    const float x = t[c][n];
    ushort h16, l16;
    bsplit(x, h16, l16);
    const size_t o = (size_t)(n0 + n) * K + k0 + c;
    Th[o] = h16;
    Tl[o] = l16;
  }
}

// ---------------------------------------------------------------------------
// bf16x3 split MFMA GEMM: C = epi(A @ B^T + bias [+ res]); 128x128, BK=32.
// MODE 0: QKV -> bf16 outputs U0/U1/U2 (q_hi,k_hi,v_hi)
// MODE 1: Wo  (+res, fp32 C + hi/lo split out)
// MODE 2: W1  (erf-GELU, hi-only bf16 out, N=3072)
// MODE 3: W2  (+res, fp32 C; A single bf16)
// ---------------------------------------------------------------------------
template <int MODE, bool ASPLIT>
__global__ __launch_bounds__(256) void mfma_gemm(
    const ushort* __restrict__ Ah, const ushort* __restrict__ Al,
    const ushort* __restrict__ B0h, const ushort* __restrict__ B0l,
    const ushort* __restrict__ B1h, const ushort* __restrict__ B1l,
    const ushort* __restrict__ B2h, const ushort* __restrict__ B2l,
    const float* __restrict__ bias0, const float* __restrict__ bias1,
    const float* __restrict__ bias2, const float* __restrict__ res,
    float* __restrict__ C0, ushort* __restrict__ Chi,
    ushort* __restrict__ Clo, ushort* __restrict__ U0,
    ushort* __restrict__ U1, ushort* __restrict__ U2, int Kd) {
  constexpr int NARR = ASPLIT ? 4 : 3;  // 0=Ah 1=Bh 2=Bl [3=Al]
  __shared__ ushort lds[NARR][4096];    // 8 KB each

  const int tid = threadIdx.x;
  const int w = tid >> 6, l = tid & 63;
  const int wm = w >> 1, wn = w & 1;
  const int r16 = l & 15, kg = l >> 4;
  const int bn = blockIdx.x, bm = blockIdx.y;

  const ushort* Bh = B0h;
  const ushort* Bl = B0l;
  const float* bias = bias0;
  ushort* Uout = U0;
  int colBase = bn * 128, bRow0 = bn * 128;
  if (MODE == 0) {
    const int sel = bn / 6;
    Bh = sel == 0 ? B0h : sel == 1 ? B1h : B2h;
    Bl = sel == 0 ? B0l : sel == 1 ? B1l : B2l;
    bias = sel == 0 ? bias0 : sel == 1 ? bias1 : bias2;
    Uout = sel == 0 ? U0 : sel == 1 ? U1 : U2;
    colBase = (bn % 6) * 128;
    bRow0 = colBase;
  }
  const int aRow0 = bm * 128;
  const int N = (MODE == 2) ? Fn : Dn;

  f4acc acc[4][4] = {};

  for (int k0 = 0; k0 < Kd; k0 += 32) {
    __syncthreads();
#pragma unroll
    for (int ii = 0; ii < 2; ++ii) {
      const int row = ii * 64 + l;
      const size_t aoff = (size_t)(aRow0 + row) * Kd + k0 + w * 8;
      const size_t boff = (size_t)(bRow0 + row) * Kd + k0 + w * 8;
      const int ldsOff = (w * 128 + ii * 64) * 8;
      gload16(Ah + aoff, &lds[0][ldsOff]);
      gload16(Bh + boff, &lds[1][ldsOff]);
      gload16(Bl + boff, &lds[2][ldsOff]);
      if (ASPLIT) gload16(Al + aoff, &lds[NARR - 1][ldsOff]);
    }
    __syncthreads();

    bfrag ah[4], al[4], bh[4], bl[4];
#pragma unroll
    for (int m = 0; m < 4; ++m) {
      const int p = (kg * 128 + wm * 64 + m * 16 + r16) * 8;
      ah[m] = *(const bfrag*)&lds[0][p];
      if (ASPLIT) al[m] = *(const bfrag*)&lds[NARR - 1][p];
    }
#pragma unroll
    for (int n = 0; n < 4; ++n) {
      const int p = (kg * 128 + wn * 64 + n * 16 + r16) * 8;
      bh[n] = *(const bfrag*)&lds[1][p];
      bl[n] = *(const bfrag*)&lds[2][p];
    }
#pragma unroll
    for (int m = 0; m < 4; ++m)
#pragma unroll
      for (int n = 0; n < 4; ++n) {
        acc[m][n] = mfma16(ah[m], bh[n], acc[m][n]);
        acc[m][n] = mfma16(ah[m], bl[n], acc[m][n]);
        if (ASPLIT) acc[m][n] = mfma16(al[m], bh[n], acc[m][n]);
      }
  }

  float bc[4];
#pragma unroll
  for (int n = 0; n < 4; ++n) bc[n] = bias[colBase + wn * 64 + n * 16 + r16];

#pragma unroll
  for (int m = 0; m < 4; ++m)
#pragma unroll
    for (int e = 0; e < 4; ++e) {
      const int grow = aRow0 + wm * 64 + m * 16 + (l >> 4) * 4 + e;
#pragma unroll
      for (int n = 0; n < 4; ++n) {
        const int gcol = colBase + wn * 64 + n * 16 + r16;
        const size_t o = (size_t)grow * N + gcol;
        float v = acc[m][n][e] + bc[n];
        if (MODE == 0) {
          Uout[o] = rne_bf16(v);
        } else if (MODE == 1) {
          v += res[o];
          C0[o] = v;
          ushort h16, l16;
          bsplit(v, h16, l16);
          Chi[o] = h16;
          Clo[o] = l16;
        } else if (MODE == 2) {
          v = 0.5f * v * (1.f + erff(v * 0.70710678118654752f));
          Chi[o] = rne_bf16(v);
        } else {  // MODE 3
          v += res[o];
          C0[o] = v;
        }
      }
    }
}

// ---------------------------------------------------------------------------
// Flash-style MFMA attention v3: TWO-PASS, normalization fused in.
// Block = (i-tile of 64 rows, b*12+h). 4 waves. JBLK=64; 16 j-tiles.
// PASS 1: per jt stage K+adjoin, QK^T MFMA, exp, accumulate PER-LANE rowsum
//         partials (no cross-lane work in loop). Reduce once at end -> inv.
// PASS 2: per jt stage K/V/adjoin again (adjoin from L3), QK^T again,
//         P = exp*inv (normalized) -> bf16 LDS, PV MFMA -> ctx normalized,
//         NONTEMPORAL coalesced writeback of normalized attn.
// attn_norm kernel eliminated (saves 805 MB of HBM traffic).
// ---------------------------------------------------------------------------
__global__ __launch_bounds__(256, 3) void attn_kernel(
    const ushort* __restrict__ q_hi, const ushort* __restrict__ k_hi,
    const ushort* __restrict__ v_hi, const float* __restrict__ mask,
    const float* __restrict__ adjoin, float* __restrict__ attn,
    float* __restrict__ ctx) {
  __shared__ __align__(16) char sm[43264];
  char* Ks = sm;                          // [64][64] bf16, swz128  (8 KB)
  char* Vs = sm + 8192;                   // [64][64] bf16, swzV128 (8 KB)
  char* Ps = sm + 16384;                  // [64][64] bf16, swz128  (8 KB)
  float* AdjS = (float*)(sm + 24576);     // [64][68] f32 padded    (17 KB)
  float* rsumLds = (float*)(sm + 41984);  // [4][64]
  float* invLds = (float*)(sm + 43008);   // [64]

  const int tid = threadIdx.x;
  const int w = tid >> 6, l = tid & 63;
  const int i0 = blockIdx.x * 64;
  const int bh = blockIdx.y;
  const int b = bh / Hn, h = bh % Hn;
  const int l4 = l & 15, lg = l >> 4;
  const int jl = 16 * w + l4;  // this lane's score column within j-tile

  // ---- Q tile in registers: qa[kk][m] = A-frag rows 16m+l4, k kk*32.. ----
  bfrag qa[2][4];
#pragma unroll
  for (int kk = 0; kk < 2; ++kk)
#pragma unroll
    for (int m = 0; m < 4; ++m)
      qa[kk][m] = *(const bfrag*)(q_hi +
          (size_t)(b * Sn + i0 + 16 * m + l4) * Dn + h * DHn + kk * 32 + lg * 8);

  const size_t attn_base = ((size_t)bh * Sn + i0) * Sn;
  const int stg_r = tid >> 3, stg_s = tid & 7;     // K/V staging map
  const int adj_r = tid >> 4, adj_f = tid & 15;    // adjoin staging map

  // ================= PASS 1: rowsums =================
  float rsP[4][4] = {};
  for (int jt = 0; jt < 16; ++jt) {
    const int j0 = jt * 64;
    uint4 kr[2];
    float4 ar[4];
#pragma unroll
    for (int u = 0; u < 2; ++u) {
      const int r = stg_r + 32 * u;
      kr[u] = *(const uint4*)(k_hi + (size_t)(b * Sn + j0 + r) * Dn + h * DHn +
                              stg_s * 8);
    }
#pragma unroll
    for (int u = 0; u < 4; ++u) {
      const int r = adj_r + 16 * u;
      ar[u] = *(const float4*)(adjoin + (size_t)(b * Sn + i0 + r) * Sn + j0 +
                               adj_f * 4);
    }
    const float mval = mask[b * Sn + j0 + jl] * (-1e9f);

    __syncthreads();
#pragma unroll
    for (int u = 0; u < 2; ++u)
      *(uint4*)(Ks + swz128(stg_r + 32 * u, stg_s * 16)) = kr[u];
#pragma unroll
    for (int u = 0; u < 4; ++u)
      *(float4*)(AdjS + (adj_r + 16 * u) * 68 + adj_f * 4) = ar[u];
    __syncthreads();

    f4acc s[4] = {};
#pragma unroll
    for (int kk = 0; kk < 2; ++kk) {
      bfrag kb2 = *(const bfrag*)(Ks + swz128(jl, kk * 64 + lg * 16));
#pragma unroll
      for (int m = 0; m < 4; ++m) s[m] = mfma16(qa[kk][m], kb2, s[m]);
    }
#pragma unroll
    for (int m = 0; m < 4; ++m)
#pragma unroll
      for (int e = 0; e < 4; ++e) {
        const int i = 16 * m + lg * 4 + e;
        const float sv = s[m][e] * 0.125f + mval + AdjS[i * 68 + jl];
        rsP[m][e] += __expf(sv);
      }
  }
  // reduce per-lane partials -> rowsums -> inv
#pragma unroll
  for (int m = 0; m < 4; ++m)
#pragma unroll
    for (int e = 0; e < 4; ++e) {
      float t = rsP[m][e];
      t += __shfl_xor(t, 1);
      t += __shfl_xor(t, 2);
      t += __shfl_xor(t, 4);
      t += __shfl_xor(t, 8);
      if (l4 == 0) rsumLds[w * 64 + 16 * m + lg * 4 + e] = t;
    }
  __syncthreads();
  if (tid < 64)
    invLds[tid] = 1.0f / (rsumLds[tid] + rsumLds[64 + tid] +
                          rsumLds[128 + tid] + rsumLds[192 + tid]);
  __syncthreads();

  float inv_i[4][4];
#pragma unroll
  for (int m = 0; m < 4; ++m)
#pragma unroll
    for (int e = 0; e < 4; ++e) inv_i[m][e] = invLds[16 * m + lg * 4 + e];

  // ================= PASS 2: normalized P, PV, writeback =================
  f4acc acc_pv[4] = {};
  for (int jt = 0; jt < 16; ++jt) {
    const int j0 = jt * 64;
    uint4 kr[2], vr[2];
    float4 ar[4];
#pragma unroll
    for (int u = 0; u < 2; ++u) {
      const int r = stg_r + 32 * u;
      const size_t gOff = (size_t)(b * Sn + j0 + r) * Dn + h * DHn + stg_s * 8;
      kr[u] = *(const uint4*)(k_hi + gOff);
      vr[u] = *(const uint4*)(v_hi + gOff);
    }
#pragma unroll
    for (int u = 0; u < 4; ++u) {
      const int r = adj_r + 16 * u;
      ar[u] = *(const float4*)(adjoin + (size_t)(b * Sn + i0 + r) * Sn + j0 +
                               adj_f * 4);
    }
    const float mval = mask[b * Sn + j0 + jl] * (-1e9f);

    __syncthreads();  // prev jt PV/writeback done
#pragma unroll
    for (int u = 0; u < 2; ++u) {
      const int r = stg_r + 32 * u;
      *(uint4*)(Ks + swz128(r, stg_s * 16)) = kr[u];
      *(uint4*)(Vs + swzV128(r, stg_s * 16)) = vr[u];
    }
#pragma unroll
    for (int u = 0; u < 4; ++u)
      *(float4*)(AdjS + (adj_r + 16 * u) * 68 + adj_f * 4) = ar[u];
    __syncthreads();  // tiles ready

    f4acc s[4] = {};
#pragma unroll
    for (int kk = 0; kk < 2; ++kk) {
      bfrag kb2 = *(const bfrag*)(Ks + swz128(jl, kk * 64 + lg * 16));
#pragma unroll
      for (int m = 0; m < 4; ++m) s[m] = mfma16(qa[kk][m], kb2, s[m]);
    }
#pragma unroll
    for (int m = 0; m < 4; ++m)
#pragma unroll
      for (int e = 0; e < 4; ++e) {
        const int i = 16 * m + lg * 4 + e;
        const float sv = s[m][e] * 0.125f + mval + AdjS[i * 68 + jl];
        const float p = __expf(sv) * inv_i[m][e];
        *(ushort*)(Ps + swz128(i, jl * 2)) = rne_bf16(p);
      }
    __syncthreads();  // P ready

    // ---- PV: wave owns d-strip [16w,16w+16) ----
#pragma unroll
    for (int kk = 0; kk < 2; ++kk) {
      bfrag pa[4], vbf;
#pragma unroll
      for (int m = 0; m < 4; ++m)
        pa[m] = *(const bfrag*)(Ps + swz128(16 * m + l4, kk * 64 + lg * 16));
#pragma unroll
      for (int e = 0; e < 8; ++e) {
        const int j = kk * 32 + lg * 8 + e;
        vbf[e] = *(const short*)(Vs + swzV128(j, (16 * w + l4) * 2));
      }
#pragma unroll
      for (int m = 0; m < 4; ++m) acc_pv[m] = mfma16(pa[m], vbf, acc_pv[m]);
    }

    // ---- coalesced NONTEMPORAL attn writeback (normalized, from Ps) ----
    {
      const int r = tid >> 2, c = tid & 3;
      const bfrag p0 = *(const bfrag*)(Ps + swz128(r, c * 32));
      const bfrag p1 = *(const bfrag*)(Ps + swz128(r, c * 32 + 16));
      f4v f0, f1, f2, f3;
      f0.x = bf2f((ushort)p0[0]); f0.y = bf2f((ushort)p0[1]);
      f0.z = bf2f((ushort)p0[2]); f0.w = bf2f((ushort)p0[3]);
      f1.x = bf2f((ushort)p0[4]); f1.y = bf2f((ushort)p0[5]);
      f1.z = bf2f((ushort)p0[6]); f1.w = bf2f((ushort)p0[7]);
      f2.x = bf2f((ushort)p1[0]); f2.y = bf2f((ushort)p1[1]);
      f2.z = bf2f((ushort)p1[2]); f2.w = bf2f((ushort)p1[3]);
      f3.x = bf2f((ushort)p1[4]); f3.y = bf2f((ushort)p1[5]);
      f3.z = bf2f((ushort)p1[6]); f3.w = bf2f((ushort)p1[7]);
      f4v* gp = (f4v*)(attn + attn_base + (size_t)r * Sn + j0 + c * 16);
      __builtin_nontemporal_store(f0, gp);
      __builtin_nontemporal_store(f1, gp + 1);
      __builtin_nontemporal_store(f2, gp + 2);
      __builtin_nontemporal_store(f3, gp + 3);
    }
  }

  // ---- ctx epilogue (already normalized) ----
#pragma unroll
  for (int m = 0; m < 4; ++m)
#pragma unroll
    for (int e = 0; e < 4; ++e) {
      const int i = 16 * m + lg * 4 + e;
      ctx[(size_t)(b * Sn + i0 + i) * Dn + h * DHn + 16 * w + l4] =
          acc_pv[m][e];
    }
}

// ---------------------------------------------------------------------------
// LayerNorm over last dim (768), one block per row.
// ---------------------------------------------------------------------------
__global__ __launch_bounds__(256) void ln_kernel(
    const float* __restrict__ xin, const float* __restrict__ gamma,
    const float* __restrict__ beta, float* __restrict__ out) {
  const int row = blockIdx.x;
  const float* xr = xin + (size_t)row * Dn;
  const int tid = threadIdx.x;
  const float v0 = xr[tid];
  const float v1 = xr[tid + 256];
  const float v2 = xr[tid + 512];
  float s = v0 + v1 + v2;
  float s2 = v0 * v0 + v1 * v1 + v2 * v2;
#pragma unroll
  for (int off = 32; off > 0; off >>= 1) {
    s += __shfl_xor(s, off);
    s2 += __shfl_xor(s2, off);
  }
  __shared__ float red[2][4];
  const int w = tid >> 6, l = tid & 63;
  if (l == 0) { red[0][w] = s; red[1][w] = s2; }
  __syncthreads();
  s = red[0][0] + red[0][1] + red[0][2] + red[0][3];
  s2 = red[1][0] + red[1][1] + red[1][2] + red[1][3];
  const float mu = s * (1.f / 768.f);
  const float var = s2 * (1.f / 768.f) - mu * mu;
  const float inv = 1.0f / sqrtf(var + 1e-6f);
  out[(size_t)row * Dn + tid] = (v0 - mu) * inv * gamma[tid] + beta[tid];
  out[(size_t)row * Dn + tid + 256] =
      (v1 - mu) * inv * gamma[tid + 256] + beta[tid + 256];
  out[(size_t)row * Dn + tid + 512] =
      (v2 - mu) * inv * gamma[tid + 512] + beta[tid + 512];
}

}  // namespace

extern "C" void kernel_launch(void* const* d_in, const int* in_sizes, int n_in,
                              void* d_out, int out_size, void* d_ws,
                              size_t ws_size, hipStream_t stream) {
  const float* x = (const float*)d_in[0];
  const float* mask = (const float*)d_in[2];
  const float* adjoin = (const float*)d_in[3];
  const float* Wq = (const float*)d_in[4];
  const float* bq = (const float*)d_in[5];
  const float* Wk = (const float*)d_in[6];
  const float* bk = (const float*)d_in[7];
  const float* Wv = (const float*)d_in[8];
  const float* bv = (const float*)d_in[9];
  const float* Wo = (const float*)d_in[10];
  const float* bo = (const float*)d_in[11];
  const float* W1 = (const float*)d_in[12];
  const float* b1 = (const float*)d_in[13];
  const float* W2 = (const float*)d_in[14];
  const float* b2 = (const float*)d_in[15];
  const float* gamma2 = (const float*)d_in[16];
  const float* beta2 = (const float*)d_in[17];

  float* out2 = (float*)d_out;               // [B,S,D]
  float* attn = out2 + (size_t)Mrows * Dn;   // [B,H,S,S]

  // ---- workspace layout (bytes); peak 115.6 MB ----
  char* ws = (char*)d_ws;
  const size_t BFS = (size_t)Mrows * Dn * 2;   // 12,582,912 (bf16 token map)
  const size_t F32S = (size_t)Mrows * Dn * 4;  // 25,165,824
  ushort* q_hi = (ushort*)(ws);
  ushort* k_hi = (ushort*)(ws + BFS);
  ushort* v_hi = (ushort*)(ws + 2 * BFS);
  float* ctx = (float*)(ws + 3 * BFS);
  ushort* ctx_hi = (ushort*)(ws + 3 * BFS + F32S);
  ushort* ctx_lo = (ushort*)(ws + 4 * BFS + F32S);
  float* out1 = (float*)(ws + 5 * BFS + F32S);
  ushort* out1_hi = (ushort*)(ws);                  // over q_hi (dead)
  ushort* out1_lo = (ushort*)(ws + BFS);            // over k_hi (dead)
  ushort* h_hi = (ushort*)(ws + 2 * BFS);           // over v_hi+ctx+ctx_hi
  const size_t WDD = (size_t)Dn * Dn * 2;           // 1.18 MB
  const size_t WDF = (size_t)Dn * Fn * 2;           // 4.72 MB
  char* wsW = ws + 5 * BFS + 2 * F32S;
  ushort* wot_hi = (ushort*)(wsW);
  ushort* wot_lo = (ushort*)(wsW + WDD);

  // ---- d_out scratch: out2 region dead until ln (step 8) ----
  char* o2r = (char*)out2;
  ushort* w1t_hi = (ushort*)(o2r);
  ushort* w1t_lo = (ushort*)(o2r + WDF);
  ushort* w2t_hi = (ushort*)(o2r + 2 * WDF);
  ushort* w2t_lo = (ushort*)(o2r + 3 * WDF);

  // ---- d_out scratch: attn region dead until attn_kernel (step 3) ----
  char* scr = (char*)attn;
  ushort* x_hi = (ushort*)(scr);
  ushort* x_lo = (ushort*)(scr + BFS);
  ushort* wqt_hi = (ushort*)(scr + 2 * BFS);
  ushort* wqt_lo = (ushort*)(scr + 2 * BFS + WDD);
  ushort* wkt_hi = (ushort*)(scr + 2 * BFS + 2 * WDD);
  ushort* wkt_lo = (ushort*)(scr + 2 * BFS + 3 * WDD);
  ushort* wvt_hi = (ushort*)(scr + 2 * BFS + 4 * WDD);
  ushort* wvt_lo = (ushort*)(scr + 2 * BFS + 5 * WDD);

  const dim3 blk(256);

  // 1) input splits + weight transpose-splits
  split_rows<<<dim3(2048), blk, 0, stream>>>((const float4*)x, x_hi, x_lo,
                                             Mrows * Dn / 4);
  transpose_split<<<dim3(12, 12), blk, 0, stream>>>(Wq, wqt_hi, wqt_lo, Dn, Dn);
  transpose_split<<<dim3(12, 12), blk, 0, stream>>>(Wk, wkt_hi, wkt_lo, Dn, Dn);
  transpose_split<<<dim3(12, 12), blk, 0, stream>>>(Wv, wvt_hi, wvt_lo, Dn, Dn);
  transpose_split<<<dim3(12, 12), blk, 0, stream>>>(Wo, wot_hi, wot_lo, Dn, Dn);
  transpose_split<<<dim3(48, 12), blk, 0, stream>>>(W1, w1t_hi, w1t_lo, Dn, Fn);
  transpose_split<<<dim3(12, 48), blk, 0, stream>>>(W2, w2t_hi, w2t_lo, Fn, Dn);

  // 2) fused QKV projection -> bf16 q/k/v
  mfma_gemm<0, true><<<dim3(18, 64), blk, 0, stream>>>(
      x_hi, x_lo, wqt_hi, wqt_lo, wkt_hi, wkt_lo, wvt_hi, wvt_lo, bq, bk, bv,
      nullptr, nullptr, nullptr, nullptr, q_hi, k_hi, v_hi, Dn);

  // 3) flash attention v3 (attn normalized in-kernel; ctx normalized)
  attn_kernel<<<dim3(Sn / 64, Bn * Hn), blk, 0, stream>>>(
      q_hi, k_hi, v_hi, mask, adjoin, attn, ctx);

  // 4) split ctx for Wo GEMM
  split_rows<<<dim3(2048), blk, 0, stream>>>((const float4*)ctx, ctx_hi, ctx_lo,
                                             Mrows * Dn / 4);

  // 5) out1 = x + ctx @ Wo + bo  (+ hi/lo split)
  mfma_gemm<1, true><<<dim3(6, 64), blk, 0, stream>>>(
      ctx_hi, ctx_lo, wot_hi, wot_lo, nullptr, nullptr, nullptr, nullptr, bo,
      nullptr, nullptr, x, out1, out1_hi, out1_lo, nullptr, nullptr, nullptr,
      Dn);

  // 6) h_hi = bf16(gelu(out1 @ W1 + b1))
  mfma_gemm<2, true><<<dim3(24, 64), blk, 0, stream>>>(
      out1_hi, out1_lo, w1t_hi, w1t_lo, nullptr, nullptr, nullptr, nullptr, b1,
      nullptr, nullptr, nullptr, nullptr, h_hi, nullptr, nullptr, nullptr,
      nullptr, Dn);

  // 7) out1 += h @ W2 + b2 (in place; A single-bf16)
  mfma_gemm<3, false><<<dim3(6, 64), blk, 0, stream>>>(
      h_hi, nullptr, w2t_hi, w2t_lo, nullptr, nullptr, nullptr, nullptr, b2,
      nullptr, nullptr, out1, out1, nullptr, nullptr, nullptr, nullptr,
      nullptr, Fn);

  // 8) out2 = layernorm(out1)
  ln_kernel<<<dim3(Mrows), blk, 0, stream>>>(out1, gamma2, beta2, out2);
}

// Round 8
// 923.339 us; speedup vs baseline: 3.6789x; 1.1988x over previous
//
#include <hip/hip_runtime.h>
#include <math.h>

namespace {

constexpr int Bn = 8, Sn = 1024, Dn = 768, Hn = 12, DHn = 64, Fn = 3072;
constexpr int Mrows = Bn * Sn;  // 8192 token rows

typedef __attribute__((ext_vector_type(8))) short bfrag;   // 8 bf16 = 4 VGPR
typedef __attribute__((ext_vector_type(4))) float f4acc;   // 4 f32 acc
typedef __attribute__((ext_vector_type(4))) float f4v;     // native float4

typedef const __attribute__((address_space(1))) unsigned int* gas_t;
typedef __attribute__((address_space(3))) unsigned int* las_t;

__device__ __forceinline__ void gload16(const ushort* g, ushort* l) {
  __builtin_amdgcn_global_load_lds((gas_t)g, (las_t)l, 16, 0, 0);
}

__device__ __forceinline__ f4acc mfma16(bfrag a, bfrag b, f4acc c) {
  return __builtin_amdgcn_mfma_f32_16x16x32_bf16(a, b, c, 0, 0, 0);
}

// split fp32 -> bf16 hi + bf16 lo (truncation; residual ~2^-16 rel)
__device__ __forceinline__ void bsplit(float x, ushort& h, ushort& l) {
  union { float f; unsigned u; } a; a.f = x;
  const ushort hi = (ushort)(a.u >> 16);
  union { unsigned u; float f; } hf; hf.u = (unsigned)hi << 16;
  union { float f; unsigned u; } b; b.f = x - hf.f;
  h = hi; l = (ushort)(b.u >> 16);
}

__device__ __forceinline__ ushort rne_bf16(float x) {
  union { float f; unsigned u; } a; a.f = x;
  const unsigned r = a.u + 0x7FFF + ((a.u >> 16) & 1);
  return (ushort)(r >> 16);
}

__device__ __forceinline__ float bf2f(ushort x) {
  union { unsigned u; float f; } t; t.u = ((unsigned)x) << 16;
  return t.f;
}

// ---------------------------------------------------------------------------
// Elementwise fp32 -> (hi, lo) bf16 split, vectorized.
// ---------------------------------------------------------------------------
__global__ __launch_bounds__(256) void split_rows(const float4* __restrict__ X,
                                                  ushort* __restrict__ H,
                                                  ushort* __restrict__ L,
                                                  int n4) {
  int i = blockIdx.x * 256 + threadIdx.x;
  const int stride = gridDim.x * 256;
  for (; i < n4; i += stride) {
    const float4 v = X[i];
    ushort h0, l0, h1, l1, h2, l2, h3, l3;
    bsplit(v.x, h0, l0); bsplit(v.y, h1, l1);
    bsplit(v.z, h2, l2); bsplit(v.w, h3, l3);
    ushort4 hv; hv.x = h0; hv.y = h1; hv.z = h2; hv.w = h3;
    ushort4 lv; lv.x = l0; lv.y = l1; lv.z = l2; lv.w = l3;
    *(ushort4*)&H[(size_t)i * 4] = hv;
    *(ushort4*)&L[(size_t)i * 4] = lv;
  }
}

// ---------------------------------------------------------------------------
// W[K][N] fp32 -> Th[N][K], Tl[N][K] bf16 (transpose + split). 64x64 tiles.
// ---------------------------------------------------------------------------
__global__ __launch_bounds__(256) void transpose_split(
    const float* __restrict__ W, ushort* __restrict__ Th,
    ushort* __restrict__ Tl, int K, int N) {
  __shared__ float t[64][65];
  const int k0 = blockIdx.y * 64, n0 = blockIdx.x * 64;
  const int c = threadIdx.x & 63, rg = threadIdx.x >> 6;
#pragma unroll
  for (int rr = 0; rr < 16; ++rr) {
    const int r = rg * 16 + rr;
    t[r][c] = W[(size_t)(k0 + r) * N + n0 + c];
  }
  __syncthreads();
#pragma unroll
  for (int rr = 0; rr < 16; ++rr) {
    const int n = rg * 16 + rr;
    const float x = t[c][n];
    ushort h16, l16;
    bsplit(x, h16, l16);
    const size_t o = (size_t)(n0 + n) * K + k0 + c;
    Th[o] = h16;
    Tl[o] = l16;
  }
}

// ---------------------------------------------------------------------------
// bf16x3 split MFMA GEMM: C = epi(A @ B^T + bias [+ res]); 128x128, BK=32.
// MODE 0: QKV -> bf16 U0/U1/U2 = q (plain), k (XOR-swizzled 16B chunks,
//         key j&7), v (key (j>>3)&7) -- pre-swizzled for attn's linear
//         global_load_lds staging.
// MODE 1: Wo  (+res, fp32 C + hi/lo split out)
// MODE 2: W1  (erf-GELU, hi-only bf16 out, N=3072)
// MODE 3: W2  (+res, fp32 C; A single bf16)
// ---------------------------------------------------------------------------
template <int MODE, bool ASPLIT>
__global__ __launch_bounds__(256) void mfma_gemm(
    const ushort* __restrict__ Ah, const ushort* __restrict__ Al,
    const ushort* __restrict__ B0h, const ushort* __restrict__ B0l,
    const ushort* __restrict__ B1h, const ushort* __restrict__ B1l,
    const ushort* __restrict__ B2h, const ushort* __restrict__ B2l,
    const float* __restrict__ bias0, const float* __restrict__ bias1,
    const float* __restrict__ bias2, const float* __restrict__ res,
    float* __restrict__ C0, ushort* __restrict__ Chi,
    ushort* __restrict__ Clo, ushort* __restrict__ U0,
    ushort* __restrict__ U1, ushort* __restrict__ U2, int Kd) {
  constexpr int NARR = ASPLIT ? 4 : 3;  // 0=Ah 1=Bh 2=Bl [3=Al]
  __shared__ ushort lds[NARR][4096];    // 8 KB each

  const int tid = threadIdx.x;
  const int w = tid >> 6, l = tid & 63;
  const int wm = w >> 1, wn = w & 1;
  const int r16 = l & 15, kg = l >> 4;
  const int bn = blockIdx.x, bm = blockIdx.y;

  const ushort* Bh = B0h;
  const ushort* Bl = B0l;
  const float* bias = bias0;
  ushort* Uout = U0;
  int sel = 0;
  int colBase = bn * 128, bRow0 = bn * 128;
  if (MODE == 0) {
    sel = bn / 6;
    Bh = sel == 0 ? B0h : sel == 1 ? B1h : B2h;
    Bl = sel == 0 ? B0l : sel == 1 ? B1l : B2l;
    bias = sel == 0 ? bias0 : sel == 1 ? bias1 : bias2;
    Uout = sel == 0 ? U0 : sel == 1 ? U1 : U2;
    colBase = (bn % 6) * 128;
    bRow0 = colBase;
  }
  const int aRow0 = bm * 128;
  const int N = (MODE == 2) ? Fn : Dn;

  f4acc acc[4][4] = {};

  for (int k0 = 0; k0 < Kd; k0 += 32) {
    __syncthreads();
#pragma unroll
    for (int ii = 0; ii < 2; ++ii) {
      const int row = ii * 64 + l;
      const size_t aoff = (size_t)(aRow0 + row) * Kd + k0 + w * 8;
      const size_t boff = (size_t)(bRow0 + row) * Kd + k0 + w * 8;
      const int ldsOff = (w * 128 + ii * 64) * 8;
      gload16(Ah + aoff, &lds[0][ldsOff]);
      gload16(Bh + boff, &lds[1][ldsOff]);
      gload16(Bl + boff, &lds[2][ldsOff]);
      if (ASPLIT) gload16(Al + aoff, &lds[NARR - 1][ldsOff]);
    }
    __syncthreads();

    bfrag ah[4], al[4], bh[4], bl[4];
#pragma unroll
    for (int m = 0; m < 4; ++m) {
      const int p = (kg * 128 + wm * 64 + m * 16 + r16) * 8;
      ah[m] = *(const bfrag*)&lds[0][p];
      if (ASPLIT) al[m] = *(const bfrag*)&lds[NARR - 1][p];
    }
#pragma unroll
    for (int n = 0; n < 4; ++n) {
      const int p = (kg * 128 + wn * 64 + n * 16 + r16) * 8;
      bh[n] = *(const bfrag*)&lds[1][p];
      bl[n] = *(const bfrag*)&lds[2][p];
    }
#pragma unroll
    for (int m = 0; m < 4; ++m)
#pragma unroll
      for (int n = 0; n < 4; ++n) {
        acc[m][n] = mfma16(ah[m], bh[n], acc[m][n]);
        acc[m][n] = mfma16(ah[m], bl[n], acc[m][n]);
        if (ASPLIT) acc[m][n] = mfma16(al[m], bh[n], acc[m][n]);
      }
  }

  float bc[4];
#pragma unroll
  for (int n = 0; n < 4; ++n) bc[n] = bias[colBase + wn * 64 + n * 16 + r16];

#pragma unroll
  for (int m = 0; m < 4; ++m)
#pragma unroll
    for (int e = 0; e < 4; ++e) {
      const int grow = aRow0 + wm * 64 + m * 16 + (l >> 4) * 4 + e;
#pragma unroll
      for (int n = 0; n < 4; ++n) {
        const int gcol = colBase + wn * 64 + n * 16 + r16;
        const size_t o = (size_t)grow * N + gcol;
        float v = acc[m][n][e] + bc[n];
        if (MODE == 0) {
          const ushort rb = rne_bf16(v);
          if (sel == 0) {
            Uout[o] = rb;  // q plain
          } else {
            // k/v: XOR-swizzle 16B chunks within each head-row (8 ushort
            // granule). key: k -> j&7, v -> (j>>3)&7.
            const int d = gcol & 63, hh = gcol >> 6;
            const int key = (sel == 1) ? (grow & 7) : ((grow >> 3) & 7);
            const size_t o2 = (size_t)grow * Dn + hh * DHn +
                              ((((d >> 3) ^ key)) << 3) + (d & 7);
            Uout[o2] = rb;
          }
        } else if (MODE == 1) {
          v += res[o];
          C0[o] = v;
          ushort h16, l16;
          bsplit(v, h16, l16);
          Chi[o] = h16;
          Clo[o] = l16;
        } else if (MODE == 2) {
          v = 0.5f * v * (1.f + erff(v * 0.70710678118654752f));
          Chi[o] = rne_bf16(v);
        } else {  // MODE 3
          v += res[o];
          C0[o] = v;
        }
      }
    }
}

// ---------------------------------------------------------------------------
// Flash-style MFMA attention v4: two-pass fused-normalize, QBLK=16, JBLK=128.
// Block = (16 q-rows, b*12+h); 4 waves; 8 j-tiles per pass.
// K/V staged by LINEAR global_load_lds from PRE-SWIZZLED global layout
// (swizzled reads are then bank-conflict-free). Adjoin f32 staged to
// XOR-swizzled LDS via regs. attn written normalized, 512B/row runs,
// normal cached stores (min write amplification). ctx written as hi/lo bf16
// (Wo GEMM input) directly from the epilogue.
// ---------------------------------------------------------------------------
__global__ __launch_bounds__(256, 3) void attn_kernel(
    const ushort* __restrict__ q_hi, const ushort* __restrict__ k_sw,
    const ushort* __restrict__ v_sw, const float* __restrict__ mask,
    const float* __restrict__ adjoin, float* __restrict__ attn,
    ushort* __restrict__ ctx_hi, ushort* __restrict__ ctx_lo) {
  __shared__ __align__(16) char sm[45440];
  char* Ks = sm;                           // [128][64] bf16, key r&7      16KB
  char* Vs = sm + 16384;                   // [128][64] bf16, key (r>>3)&7 16KB
  char* AdjS = sm + 32768;                 // [16][128] f32, key r&7        8KB
  char* Ps = sm + 40960;                   // [16][128] bf16, key r&7       4KB
  float* rsumLds = (float*)(sm + 45056);   // [4][16]
  float* invLds = (float*)(sm + 45312);    // [16]

  const int tid = threadIdx.x;
  const int w = tid >> 6, l = tid & 63;
  const int l4 = l & 15, lg = l >> 4;
  const int i0 = blockIdx.x * 16;
  const int bh = blockIdx.y;
  const int b = bh / Hn, h = bh % Hn;

  // ---- Q frags (plain layout): row i0+l4, k-slice kk*32+lg*8 ----
  bfrag qa[2];
#pragma unroll
  for (int kk = 0; kk < 2; ++kk)
    qa[kk] = *(const bfrag*)(q_hi + (size_t)(b * Sn + i0 + l4) * Dn + h * DHn +
                             kk * 32 + lg * 8);

  const size_t kvHead = (size_t)b * Sn * Dn + h * DHn;  // ushort offset base
  const size_t attn_base = ((size_t)bh * Sn + i0) * Sn;

  // per-lane score columns for the two n-subtiles
  const int jl0 = 32 * w + l4, jl1 = 32 * w + 16 + l4;

  // ================= PASS 1: rowsums =================
  float rsP[4] = {};
  for (int jt = 0; jt < 8; ++jt) {
    const int j0 = jt * 128;
    __syncthreads();  // prev-iter LDS readers done
    // K: 4 linear gload_lds issues (1KB per wave-issue)
#pragma unroll
    for (int u = 0; u < 4; ++u) {
      const int idx = u * 256 + w * 64 + l;
      const int r = idx >> 3, s = idx & 7;
      gload16(k_sw + kvHead + (size_t)(j0 + r) * Dn + s * 8,
              (ushort*)(Ks + u * 4096 + w * 1024));
    }
    // adjoin: 2 float4 per thread -> swizzled LDS
    float4 ar[2];
#pragma unroll
    for (int u = 0; u < 2; ++u) {
      const int idx = tid + 256 * u;
      const int r = idx >> 5, f = idx & 31;
      ar[u] = *(const float4*)(adjoin + (size_t)(b * Sn + i0 + r) * Sn + j0 +
                               f * 4);
    }
    const float mk0 = mask[b * Sn + j0 + jl0] * (-1e9f);
    const float mk1 = mask[b * Sn + j0 + jl1] * (-1e9f);
#pragma unroll
    for (int u = 0; u < 2; ++u) {
      const int idx = tid + 256 * u;
      const int r = idx >> 5, f = idx & 31;
      *(float4*)(AdjS + r * 512 + ((f * 16) ^ ((r & 7) << 4))) = ar[u];
    }
    __syncthreads();  // K (vmcnt drained) + Adj ready

    f4acc s0 = {}, s1 = {};
#pragma unroll
    for (int kk = 0; kk < 2; ++kk) {
      const int cb = kk * 64 + lg * 16;
      const bfrag k0 = *(const bfrag*)(Ks + jl0 * 128 + (cb ^ ((jl0 & 7) << 4)));
      const bfrag k1 = *(const bfrag*)(Ks + jl1 * 128 + (cb ^ ((jl1 & 7) << 4)));
      s0 = mfma16(qa[kk], k0, s0);
      s1 = mfma16(qa[kk], k1, s1);
    }
#pragma unroll
    for (int e = 0; e < 4; ++e) {
      const int i = lg * 4 + e;
      const float a0 =
          *(const float*)(AdjS + i * 512 + ((jl0 * 4) ^ ((i & 7) << 4)));
      const float a1 =
          *(const float*)(AdjS + i * 512 + ((jl1 * 4) ^ ((i & 7) << 4)));
      rsP[e] += __expf(s0[e] * 0.125f + mk0 + a0);
      rsP[e] += __expf(s1[e] * 0.125f + mk1 + a1);
    }
  }
#pragma unroll
  for (int e = 0; e < 4; ++e) {
    float t = rsP[e];
    t += __shfl_xor(t, 1);
    t += __shfl_xor(t, 2);
    t += __shfl_xor(t, 4);
    t += __shfl_xor(t, 8);
    if (l4 == 0) rsumLds[w * 16 + lg * 4 + e] = t;
  }
  __syncthreads();
  if (tid < 16)
    invLds[tid] = 1.0f / (rsumLds[tid] + rsumLds[16 + tid] + rsumLds[32 + tid] +
                          rsumLds[48 + tid]);
  __syncthreads();
  float inv_e[4];
#pragma unroll
  for (int e = 0; e < 4; ++e) inv_e[e] = invLds[lg * 4 + e];

  // ================= PASS 2: normalized P, PV, writeback =================
  f4acc apv = {};
  for (int jt = 0; jt < 8; ++jt) {
    const int j0 = jt * 128;
    __syncthreads();  // prev PV/writeback readers done
#pragma unroll
    for (int u = 0; u < 4; ++u) {
      const int idx = u * 256 + w * 64 + l;
      const int r = idx >> 3, s = idx & 7;
      const size_t rowOff = kvHead + (size_t)(j0 + r) * Dn + s * 8;
      gload16(k_sw + rowOff, (ushort*)(Ks + u * 4096 + w * 1024));
      gload16(v_sw + rowOff, (ushort*)(Vs + u * 4096 + w * 1024));
    }
    float4 ar[2];
#pragma unroll
    for (int u = 0; u < 2; ++u) {
      const int idx = tid + 256 * u;
      const int r = idx >> 5, f = idx & 31;
      ar[u] = *(const float4*)(adjoin + (size_t)(b * Sn + i0 + r) * Sn + j0 +
                               f * 4);
    }
    const float mk0 = mask[b * Sn + j0 + jl0] * (-1e9f);
    const float mk1 = mask[b * Sn + j0 + jl1] * (-1e9f);
#pragma unroll
    for (int u = 0; u < 2; ++u) {
      const int idx = tid + 256 * u;
      const int r = idx >> 5, f = idx & 31;
      *(float4*)(AdjS + r * 512 + ((f * 16) ^ ((r & 7) << 4))) = ar[u];
    }
    __syncthreads();  // tiles ready

    f4acc s0 = {}, s1 = {};
#pragma unroll
    for (int kk = 0; kk < 2; ++kk) {
      const int cb = kk * 64 + lg * 16;
      const bfrag k0 = *(const bfrag*)(Ks + jl0 * 128 + (cb ^ ((jl0 & 7) << 4)));
      const bfrag k1 = *(const bfrag*)(Ks + jl1 * 128 + (cb ^ ((jl1 & 7) << 4)));
      s0 = mfma16(qa[kk], k0, s0);
      s1 = mfma16(qa[kk], k1, s1);
    }
#pragma unroll
    for (int e = 0; e < 4; ++e) {
      const int i = lg * 4 + e;
      const float a0 =
          *(const float*)(AdjS + i * 512 + ((jl0 * 4) ^ ((i & 7) << 4)));
      const float a1 =
          *(const float*)(AdjS + i * 512 + ((jl1 * 4) ^ ((i & 7) << 4)));
      const float p0 = __expf(s0[e] * 0.125f + mk0 + a0) * inv_e[e];
      const float p1 = __expf(s1[e] * 0.125f + mk1 + a1) * inv_e[e];
      *(ushort*)(Ps + i * 256 + ((jl0 * 2) ^ ((i & 7) << 4))) = rne_bf16(p0);
      *(ushort*)(Ps + i * 256 + ((jl1 * 2) ^ ((i & 7) << 4))) = rne_bf16(p1);
    }
    __syncthreads();  // P ready (V ready since stage barrier)

    // ---- PV: wave owns d-strip [16w,16w+16) ----
#pragma unroll
    for (int kk = 0; kk < 4; ++kk) {
      const int cb = kk * 64 + lg * 16;
      const bfrag pa =
          *(const bfrag*)(Ps + l4 * 256 + (cb ^ ((l4 & 7) << 4)));
      bfrag vb;
#pragma unroll
      for (int e = 0; e < 8; ++e) {
        const int j = kk * 32 + lg * 8 + e;
        vb[e] = *(const short*)(Vs + j * 128 +
                                (((16 * w + l4) * 2) ^ (((j >> 3) & 7) << 4)));
      }
      apv = mfma16(pa, vb, apv);
    }

    // ---- attn writeback: 64 threads x 128B contiguous, 512B/row runs ----
    if (tid < 64) {
      const int r = tid >> 2, c = tid & 3;
      float* gp = attn + attn_base + (size_t)r * Sn + j0 + c * 32;
#pragma unroll
      for (int k2 = 0; k2 < 4; ++k2) {
        const bfrag pb = *(const bfrag*)(
            Ps + r * 256 + ((c * 64 + k2 * 16) ^ ((r & 7) << 4)));
        f4v f0, f1;
        f0.x = bf2f((ushort)pb[0]); f0.y = bf2f((ushort)pb[1]);
        f0.z = bf2f((ushort)pb[2]); f0.w = bf2f((ushort)pb[3]);
        f1.x = bf2f((ushort)pb[4]); f1.y = bf2f((ushort)pb[5]);
        f1.z = bf2f((ushort)pb[6]); f1.w = bf2f((ushort)pb[7]);
        *(f4v*)(gp + k2 * 8) = f0;
        *(f4v*)(gp + k2 * 8 + 4) = f1;
      }
    }
  }

  // ---- ctx epilogue: hi/lo bf16 split (Wo GEMM A-side), normalized ----
#pragma unroll
  for (int e = 0; e < 4; ++e) {
    const int i = lg * 4 + e;
    const size_t o = (size_t)(b * Sn + i0 + i) * Dn + h * DHn + 16 * w + l4;
    ushort h16, l16;
    bsplit(apv[e], h16, l16);
    ctx_hi[o] = h16;
    ctx_lo[o] = l16;
  }
}

// ---------------------------------------------------------------------------
// LayerNorm over last dim (768), one block per row.
// ---------------------------------------------------------------------------
__global__ __launch_bounds__(256) void ln_kernel(
    const float* __restrict__ xin, const float* __restrict__ gamma,
    const float* __restrict__ beta, float* __restrict__ out) {
  const int row = blockIdx.x;
  const float* xr = xin + (size_t)row * Dn;
  const int tid = threadIdx.x;
  const float v0 = xr[tid];
  const float v1 = xr[tid + 256];
  const float v2 = xr[tid + 512];
  float s = v0 + v1 + v2;
  float s2 = v0 * v0 + v1 * v1 + v2 * v2;
#pragma unroll
  for (int off = 32; off > 0; off >>= 1) {
    s += __shfl_xor(s, off);
    s2 += __shfl_xor(s2, off);
  }
  __shared__ float red[2][4];
  const int w = tid >> 6, l = tid & 63;
  if (l == 0) { red[0][w] = s; red[1][w] = s2; }
  __syncthreads();
  s = red[0][0] + red[0][1] + red[0][2] + red[0][3];
  s2 = red[1][0] + red[1][1] + red[1][2] + red[1][3];
  const float mu = s * (1.f / 768.f);
  const float var = s2 * (1.f / 768.f) - mu * mu;
  const float inv = 1.0f / sqrtf(var + 1e-6f);
  out[(size_t)row * Dn + tid] = (v0 - mu) * inv * gamma[tid] + beta[tid];
  out[(size_t)row * Dn + tid + 256] =
      (v1 - mu) * inv * gamma[tid + 256] + beta[tid + 256];
  out[(size_t)row * Dn + tid + 512] =
      (v2 - mu) * inv * gamma[tid + 512] + beta[tid + 512];
}

}  // namespace

extern "C" void kernel_launch(void* const* d_in, const int* in_sizes, int n_in,
                              void* d_out, int out_size, void* d_ws,
                              size_t ws_size, hipStream_t stream) {
  const float* x = (const float*)d_in[0];
  const float* mask = (const float*)d_in[2];
  const float* adjoin = (const float*)d_in[3];
  const float* Wq = (const float*)d_in[4];
  const float* bq = (const float*)d_in[5];
  const float* Wk = (const float*)d_in[6];
  const float* bk = (const float*)d_in[7];
  const float* Wv = (const float*)d_in[8];
  const float* bv = (const float*)d_in[9];
  const float* Wo = (const float*)d_in[10];
  const float* bo = (const float*)d_in[11];
  const float* W1 = (const float*)d_in[12];
  const float* b1 = (const float*)d_in[13];
  const float* W2 = (const float*)d_in[14];
  const float* b2 = (const float*)d_in[15];
  const float* gamma2 = (const float*)d_in[16];
  const float* beta2 = (const float*)d_in[17];

  float* out2 = (float*)d_out;               // [B,S,D]
  float* attn = out2 + (size_t)Mrows * Dn;   // [B,H,S,S]

  // ---- workspace layout (bytes) ----
  char* ws = (char*)d_ws;
  const size_t BFS = (size_t)Mrows * Dn * 2;   // 12,582,912 (bf16 token map)
  const size_t F32S = (size_t)Mrows * Dn * 4;  // 25,165,824
  ushort* q_hi = (ushort*)(ws);
  ushort* k_sw = (ushort*)(ws + BFS);
  ushort* v_sw = (ushort*)(ws + 2 * BFS);
  ushort* ctx_hi = (ushort*)(ws + 3 * BFS + F32S);
  ushort* ctx_lo = (ushort*)(ws + 4 * BFS + F32S);
  float* out1 = (float*)(ws + 5 * BFS + F32S);
  ushort* out1_hi = (ushort*)(ws);                  // over q_hi (dead)
  ushort* out1_lo = (ushort*)(ws + BFS);            // over k_sw (dead)
  ushort* h_hi = (ushort*)(ws + 2 * BFS);           // over v_sw..ctx_hi
  const size_t WDD = (size_t)Dn * Dn * 2;           // 1.18 MB
  const size_t WDF = (size_t)Dn * Fn * 2;           // 4.72 MB
  char* wsW = ws + 5 * BFS + 2 * F32S;
  ushort* wot_hi = (ushort*)(wsW);
  ushort* wot_lo = (ushort*)(wsW + WDD);

  // ---- d_out scratch: out2 region dead until ln (step 8) ----
  char* o2r = (char*)out2;
  ushort* w1t_hi = (ushort*)(o2r);
  ushort* w1t_lo = (ushort*)(o2r + WDF);
  ushort* w2t_hi = (ushort*)(o2r + 2 * WDF);
  ushort* w2t_lo = (ushort*)(o2r + 3 * WDF);

  // ---- d_out scratch: attn region dead until attn_kernel (step 3) ----
  char* scr = (char*)attn;
  ushort* x_hi = (ushort*)(scr);
  ushort* x_lo = (ushort*)(scr + BFS);
  ushort* wqt_hi = (ushort*)(scr + 2 * BFS);
  ushort* wqt_lo = (ushort*)(scr + 2 * BFS + WDD);
  ushort* wkt_hi = (ushort*)(scr + 2 * BFS + 2 * WDD);
  ushort* wkt_lo = (ushort*)(scr + 2 * BFS + 3 * WDD);
  ushort* wvt_hi = (ushort*)(scr + 2 * BFS + 4 * WDD);
  ushort* wvt_lo = (ushort*)(scr + 2 * BFS + 5 * WDD);

  const dim3 blk(256);

  // 1) input splits + weight transpose-splits
  split_rows<<<dim3(2048), blk, 0, stream>>>((const float4*)x, x_hi, x_lo,
                                             Mrows * Dn / 4);
  transpose_split<<<dim3(12, 12), blk, 0, stream>>>(Wq, wqt_hi, wqt_lo, Dn, Dn);
  transpose_split<<<dim3(12, 12), blk, 0, stream>>>(Wk, wkt_hi, wkt_lo, Dn, Dn);
  transpose_split<<<dim3(12, 12), blk, 0, stream>>>(Wv, wvt_hi, wvt_lo, Dn, Dn);
  transpose_split<<<dim3(12, 12), blk, 0, stream>>>(Wo, wot_hi, wot_lo, Dn, Dn);
  transpose_split<<<dim3(48, 12), blk, 0, stream>>>(W1, w1t_hi, w1t_lo, Dn, Fn);
  transpose_split<<<dim3(12, 48), blk, 0, stream>>>(W2, w2t_hi, w2t_lo, Fn, Dn);

  // 2) fused QKV projection -> q plain, k/v pre-swizzled bf16
  mfma_gemm<0, true><<<dim3(18, 64), blk, 0, stream>>>(
      x_hi, x_lo, wqt_hi, wqt_lo, wkt_hi, wkt_lo, wvt_hi, wvt_lo, bq, bk, bv,
      nullptr, nullptr, nullptr, nullptr, q_hi, k_sw, v_sw, Dn);

  // 3) flash attention v4 (attn normalized; ctx hi/lo split fused)
  attn_kernel<<<dim3(Sn / 16, Bn * Hn), blk, 0, stream>>>(
      q_hi, k_sw, v_sw, mask, adjoin, attn, ctx_hi, ctx_lo);

  // 5) out1 = x + ctx @ Wo + bo  (+ hi/lo split)
  mfma_gemm<1, true><<<dim3(6, 64), blk, 0, stream>>>(
      ctx_hi, ctx_lo, wot_hi, wot_lo, nullptr, nullptr, nullptr, nullptr, bo,
      nullptr, nullptr, x, out1, out1_hi, out1_lo, nullptr, nullptr, nullptr,
      Dn);

  // 6) h_hi = bf16(gelu(out1 @ W1 + b1))
  mfma_gemm<2, true><<<dim3(24, 64), blk, 0, stream>>>(
      out1_hi, out1_lo, w1t_hi, w1t_lo, nullptr, nullptr, nullptr, nullptr, b1,
      nullptr, nullptr, nullptr, nullptr, h_hi, nullptr, nullptr, nullptr,
      nullptr, Dn);

  // 7) out1 += h @ W2 + b2 (in place; A single-bf16)
  mfma_gemm<3, false><<<dim3(6, 64), blk, 0, stream>>>(
      h_hi, nullptr, w2t_hi, w2t_lo, nullptr, nullptr, nullptr, nullptr, b2,
      nullptr, nullptr, out1, out1, nullptr, nullptr, nullptr, nullptr,
      nullptr, Fn);

  // 8) out2 = layernorm(out1)
  ln_kernel<<<dim3(Mrows), blk, 0, stream>>>(out1, gamma2, beta2, out2);
}

// Round 9
// 898.732 us; speedup vs baseline: 3.7796x; 1.0274x over previous
//
#include <hip/hip_runtime.h>
#include <math.h>

namespace {

constexpr int Bn = 8, Sn = 1024, Dn = 768, Hn = 12, DHn = 64, Fn = 3072;
constexpr int Mrows = Bn * Sn;  // 8192 token rows

typedef __attribute__((ext_vector_type(8))) short bfrag;   // 8 bf16 = 4 VGPR
typedef __attribute__((ext_vector_type(4))) float f4acc;   // 4 f32 acc
typedef __attribute__((ext_vector_type(4))) float f4v;     // native float4
typedef __attribute__((ext_vector_type(8))) ushort u8v;    // 8 bf16 packed

typedef const __attribute__((address_space(1))) unsigned int* gas_t;
typedef __attribute__((address_space(3))) unsigned int* las_t;

__device__ __forceinline__ void gload16(const ushort* g, ushort* l) {
  __builtin_amdgcn_global_load_lds((gas_t)g, (las_t)l, 16, 0, 0);
}

__device__ __forceinline__ f4acc mfma16(bfrag a, bfrag b, f4acc c) {
  return __builtin_amdgcn_mfma_f32_16x16x32_bf16(a, b, c, 0, 0, 0);
}

// split fp32 -> bf16 hi + bf16 lo (truncation; residual ~2^-16 rel)
__device__ __forceinline__ void bsplit(float x, ushort& h, ushort& l) {
  union { float f; unsigned u; } a; a.f = x;
  const ushort hi = (ushort)(a.u >> 16);
  union { unsigned u; float f; } hf; hf.u = (unsigned)hi << 16;
  union { float f; unsigned u; } b; b.f = x - hf.f;
  h = hi; l = (ushort)(b.u >> 16);
}

__device__ __forceinline__ ushort rne_bf16(float x) {
  union { float f; unsigned u; } a; a.f = x;
  const unsigned r = a.u + 0x7FFF + ((a.u >> 16) & 1);
  return (ushort)(r >> 16);
}

__device__ __forceinline__ float bf2f(ushort x) {
  union { unsigned u; float f; } t; t.u = ((unsigned)x) << 16;
  return t.f;
}

// ---------------------------------------------------------------------------
// Elementwise fp32 -> (hi, lo) bf16 split, vectorized.
// ---------------------------------------------------------------------------
__global__ __launch_bounds__(256) void split_rows(const float4* __restrict__ X,
                                                  ushort* __restrict__ H,
                                                  ushort* __restrict__ L,
                                                  int n4) {
  int i = blockIdx.x * 256 + threadIdx.x;
  const int stride = gridDim.x * 256;
  for (; i < n4; i += stride) {
    const float4 v = X[i];
    ushort h0, l0, h1, l1, h2, l2, h3, l3;
    bsplit(v.x, h0, l0); bsplit(v.y, h1, l1);
    bsplit(v.z, h2, l2); bsplit(v.w, h3, l3);
    ushort4 hv; hv.x = h0; hv.y = h1; hv.z = h2; hv.w = h3;
    ushort4 lv; lv.x = l0; lv.y = l1; lv.z = l2; lv.w = l3;
    *(ushort4*)&H[(size_t)i * 4] = hv;
    *(ushort4*)&L[(size_t)i * 4] = lv;
  }
}

// ---------------------------------------------------------------------------
// W[K][N] fp32 -> Th[N][K], Tl[N][K] bf16 (transpose + split). 64x64 tiles.
// ---------------------------------------------------------------------------
__global__ __launch_bounds__(256) void transpose_split(
    const float* __restrict__ W, ushort* __restrict__ Th,
    ushort* __restrict__ Tl, int K, int N) {
  __shared__ float t[64][65];
  const int k0 = blockIdx.y * 64, n0 = blockIdx.x * 64;
  const int c = threadIdx.x & 63, rg = threadIdx.x >> 6;
#pragma unroll
  for (int rr = 0; rr < 16; ++rr) {
    const int r = rg * 16 + rr;
    t[r][c] = W[(size_t)(k0 + r) * N + n0 + c];
  }
  __syncthreads();
#pragma unroll
  for (int rr = 0; rr < 16; ++rr) {
    const int n = rg * 16 + rr;
    const float x = t[c][n];
    ushort h16, l16;
    bsplit(x, h16, l16);
    const size_t o = (size_t)(n0 + n) * K + k0 + c;
    Th[o] = h16;
    Tl[o] = l16;
  }
}

// ---------------------------------------------------------------------------
// bf16x3 split MFMA GEMM: C = epi(A @ B^T + bias [+ res]); 128x128, BK=32.
// MODE 0: QKV -> bf16 U0/U1/U2 = q (plain), k (XOR-swizzled 16B chunks,
//         key j&7), v (key (j>>3)&7) -- pre-swizzled for attn's linear
//         global_load_lds staging.
// MODE 1: Wo  (+res, fp32 C + hi/lo split out)
// MODE 2: W1  (erf-GELU, hi-only bf16 out, N=3072)
// MODE 3: W2  (+res, fp32 C; A single bf16)
// ---------------------------------------------------------------------------
template <int MODE, bool ASPLIT>
__global__ __launch_bounds__(256) void mfma_gemm(
    const ushort* __restrict__ Ah, const ushort* __restrict__ Al,
    const ushort* __restrict__ B0h, const ushort* __restrict__ B0l,
    const ushort* __restrict__ B1h, const ushort* __restrict__ B1l,
    const ushort* __restrict__ B2h, const ushort* __restrict__ B2l,
    const float* __restrict__ bias0, const float* __restrict__ bias1,
    const float* __restrict__ bias2, const float* __restrict__ res,
    float* __restrict__ C0, ushort* __restrict__ Chi,
    ushort* __restrict__ Clo, ushort* __restrict__ U0,
    ushort* __restrict__ U1, ushort* __restrict__ U2, int Kd) {
  constexpr int NARR = ASPLIT ? 4 : 3;  // 0=Ah 1=Bh 2=Bl [3=Al]
  __shared__ ushort lds[NARR][4096];    // 8 KB each

  const int tid = threadIdx.x;
  const int w = tid >> 6, l = tid & 63;
  const int wm = w >> 1, wn = w & 1;
  const int r16 = l & 15, kg = l >> 4;
  const int bn = blockIdx.x, bm = blockIdx.y;

  const ushort* Bh = B0h;
  const ushort* Bl = B0l;
  const float* bias = bias0;
  ushort* Uout = U0;
  int sel = 0;
  int colBase = bn * 128, bRow0 = bn * 128;
  if (MODE == 0) {
    sel = bn / 6;
    Bh = sel == 0 ? B0h : sel == 1 ? B1h : B2h;
    Bl = sel == 0 ? B0l : sel == 1 ? B1l : B2l;
    bias = sel == 0 ? bias0 : sel == 1 ? bias1 : bias2;
    Uout = sel == 0 ? U0 : sel == 1 ? U1 : U2;
    colBase = (bn % 6) * 128;
    bRow0 = colBase;
  }
  const int aRow0 = bm * 128;
  const int N = (MODE == 2) ? Fn : Dn;

  f4acc acc[4][4] = {};

  for (int k0 = 0; k0 < Kd; k0 += 32) {
    __syncthreads();
#pragma unroll
    for (int ii = 0; ii < 2; ++ii) {
      const int row = ii * 64 + l;
      const size_t aoff = (size_t)(aRow0 + row) * Kd + k0 + w * 8;
      const size_t boff = (size_t)(bRow0 + row) * Kd + k0 + w * 8;
      const int ldsOff = (w * 128 + ii * 64) * 8;
      gload16(Ah + aoff, &lds[0][ldsOff]);
      gload16(Bh + boff, &lds[1][ldsOff]);
      gload16(Bl + boff, &lds[2][ldsOff]);
      if (ASPLIT) gload16(Al + aoff, &lds[NARR - 1][ldsOff]);
    }
    __syncthreads();

    bfrag ah[4], al[4], bh[4], bl[4];
#pragma unroll
    for (int m = 0; m < 4; ++m) {
      const int p = (kg * 128 + wm * 64 + m * 16 + r16) * 8;
      ah[m] = *(const bfrag*)&lds[0][p];
      if (ASPLIT) al[m] = *(const bfrag*)&lds[NARR - 1][p];
    }
#pragma unroll
    for (int n = 0; n < 4; ++n) {
      const int p = (kg * 128 + wn * 64 + n * 16 + r16) * 8;
      bh[n] = *(const bfrag*)&lds[1][p];
      bl[n] = *(const bfrag*)&lds[2][p];
    }
#pragma unroll
    for (int m = 0; m < 4; ++m)
#pragma unroll
      for (int n = 0; n < 4; ++n) {
        acc[m][n] = mfma16(ah[m], bh[n], acc[m][n]);
        acc[m][n] = mfma16(ah[m], bl[n], acc[m][n]);
        if (ASPLIT) acc[m][n] = mfma16(al[m], bh[n], acc[m][n]);
      }
  }

  float bc[4];
#pragma unroll
  for (int n = 0; n < 4; ++n) bc[n] = bias[colBase + wn * 64 + n * 16 + r16];

#pragma unroll
  for (int m = 0; m < 4; ++m)
#pragma unroll
    for (int e = 0; e < 4; ++e) {
      const int grow = aRow0 + wm * 64 + m * 16 + (l >> 4) * 4 + e;
#pragma unroll
      for (int n = 0; n < 4; ++n) {
        const int gcol = colBase + wn * 64 + n * 16 + r16;
        const size_t o = (size_t)grow * N + gcol;
        float v = acc[m][n][e] + bc[n];
        if (MODE == 0) {
          const ushort rb = rne_bf16(v);
          if (sel == 0) {
            Uout[o] = rb;  // q plain
          } else {
            // k/v: XOR-swizzle 16B chunks within each head-row (8 ushort
            // granule). key: k -> j&7, v -> (j>>3)&7.
            const int d = gcol & 63, hh = gcol >> 6;
            const int key = (sel == 1) ? (grow & 7) : ((grow >> 3) & 7);
            const size_t o2 = (size_t)grow * Dn + hh * DHn +
                              ((((d >> 3) ^ key)) << 3) + (d & 7);
            Uout[o2] = rb;
          }
        } else if (MODE == 1) {
          v += res[o];
          C0[o] = v;
          ushort h16, l16;
          bsplit(v, h16, l16);
          Chi[o] = h16;
          Clo[o] = l16;
        } else if (MODE == 2) {
          v = 0.5f * v * (1.f + erff(v * 0.70710678118654752f));
          Chi[o] = rne_bf16(v);
        } else {  // MODE 3
          v += res[o];
          C0[o] = v;
        }
      }
    }
}

// ---------------------------------------------------------------------------
// Flash-style MFMA attention v5: SINGLE PASS, P cached in registers.
// Block = (16 q-rows, b*12+h); 4 waves; 8 j-tiles. K/V staged by linear
// global_load_lds from pre-swizzled global; adjoin f32 -> swizzled LDS.
// Main loop: QK^T MFMA -> exp (unnormalized) -> pack bf16 into p_reg[jt]
// (fully unrolled, static idx) + Ps LDS -> PV MFMA (unnormalized acc).
// After rowsum reduce: writeback phase re-normalizes p_reg -> Ps -> coalesced
// 512B/row attn stores (all 256 threads). ctx scaled by inv in epilogue,
// written as hi/lo bf16 (Wo GEMM A input).
// ---------------------------------------------------------------------------
__global__ __launch_bounds__(256, 3) void attn_kernel(
    const ushort* __restrict__ q_hi, const ushort* __restrict__ k_sw,
    const ushort* __restrict__ v_sw, const float* __restrict__ mask,
    const float* __restrict__ adjoin, float* __restrict__ attn,
    ushort* __restrict__ ctx_hi, ushort* __restrict__ ctx_lo) {
  __shared__ __align__(16) char sm[45440];
  char* Ks = sm;                           // [128][64] bf16, key r&7      16KB
  char* Vs = sm + 16384;                   // [128][64] bf16, key (r>>3)&7 16KB
  char* AdjS = sm + 32768;                 // [16][128] f32, key r&7        8KB
  char* Ps = sm + 40960;                   // [16][128] bf16, key r&7       4KB
  float* rsumLds = (float*)(sm + 45056);   // [4][16]
  float* invLds = (float*)(sm + 45312);    // [16]

  const int tid = threadIdx.x;
  const int w = tid >> 6, l = tid & 63;
  const int l4 = l & 15, lg = l >> 4;
  const int i0 = blockIdx.x * 16;
  const int bh = blockIdx.y;
  const int b = bh / Hn, h = bh % Hn;

  // ---- Q frags (plain layout): row i0+l4, k-slice kk*32+lg*8 ----
  bfrag qa[2];
#pragma unroll
  for (int kk = 0; kk < 2; ++kk)
    qa[kk] = *(const bfrag*)(q_hi + (size_t)(b * Sn + i0 + l4) * Dn + h * DHn +
                             kk * 32 + lg * 8);

  const size_t kvHead = (size_t)b * Sn * Dn + h * DHn;  // ushort offset base
  const size_t attn_base = ((size_t)bh * Sn + i0) * Sn;

  // per-lane score columns for the two n-subtiles
  const int jl0 = 32 * w + l4, jl1 = 32 * w + 16 + l4;

  // ================= MAIN LOOP (single pass) =================
  u8v p_reg[8];       // unnormalized exp, bf16-packed: [jt]{e: col jl0, 4+e: jl1}
  float rsP[4] = {};  // per-lane rowsum partials
  f4acc apv = {};     // UNNORMALIZED PV accumulator

#pragma unroll
  for (int jt = 0; jt < 8; ++jt) {
    const int j0 = jt * 128;
    __syncthreads();  // prev-iter LDS readers done
#pragma unroll
    for (int u = 0; u < 4; ++u) {
      const int idx = u * 256 + w * 64 + l;
      const int r = idx >> 3, s = idx & 7;
      const size_t rowOff = kvHead + (size_t)(j0 + r) * Dn + s * 8;
      gload16(k_sw + rowOff, (ushort*)(Ks + u * 4096 + w * 1024));
      gload16(v_sw + rowOff, (ushort*)(Vs + u * 4096 + w * 1024));
    }
    float4 ar[2];
#pragma unroll
    for (int u = 0; u < 2; ++u) {
      const int idx = tid + 256 * u;
      const int r = idx >> 5, f = idx & 31;
      ar[u] = *(const float4*)(adjoin + (size_t)(b * Sn + i0 + r) * Sn + j0 +
                               f * 4);
    }
    const float mk0 = mask[b * Sn + j0 + jl0] * (-1e9f);
    const float mk1 = mask[b * Sn + j0 + jl1] * (-1e9f);
#pragma unroll
    for (int u = 0; u < 2; ++u) {
      const int idx = tid + 256 * u;
      const int r = idx >> 5, f = idx & 31;
      *(float4*)(AdjS + r * 512 + ((f * 16) ^ ((r & 7) << 4))) = ar[u];
    }
    __syncthreads();  // K/V (vmcnt drained) + Adj ready

    f4acc s0 = {}, s1 = {};
#pragma unroll
    for (int kk = 0; kk < 2; ++kk) {
      const int cb = kk * 64 + lg * 16;
      const bfrag k0 = *(const bfrag*)(Ks + jl0 * 128 + (cb ^ ((jl0 & 7) << 4)));
      const bfrag k1 = *(const bfrag*)(Ks + jl1 * 128 + (cb ^ ((jl1 & 7) << 4)));
      s0 = mfma16(qa[kk], k0, s0);
      s1 = mfma16(qa[kk], k1, s1);
    }
#pragma unroll
    for (int e = 0; e < 4; ++e) {
      const int i = lg * 4 + e;
      const float a0 =
          *(const float*)(AdjS + i * 512 + ((jl0 * 4) ^ ((i & 7) << 4)));
      const float a1 =
          *(const float*)(AdjS + i * 512 + ((jl1 * 4) ^ ((i & 7) << 4)));
      const float ev0 = __expf(s0[e] * 0.125f + mk0 + a0);
      const float ev1 = __expf(s1[e] * 0.125f + mk1 + a1);
      rsP[e] += ev0 + ev1;
      const ushort b0 = rne_bf16(ev0), b1 = rne_bf16(ev1);
      p_reg[jt][e] = b0;
      p_reg[jt][4 + e] = b1;
      *(ushort*)(Ps + i * 256 + ((jl0 * 2) ^ ((i & 7) << 4))) = b0;
      *(ushort*)(Ps + i * 256 + ((jl1 * 2) ^ ((i & 7) << 4))) = b1;
    }
    __syncthreads();  // P ready

    // ---- PV (unnormalized): wave owns d-strip [16w,16w+16) ----
#pragma unroll
    for (int kk = 0; kk < 4; ++kk) {
      const int cb = kk * 64 + lg * 16;
      const bfrag pa =
          *(const bfrag*)(Ps + l4 * 256 + (cb ^ ((l4 & 7) << 4)));
      bfrag vb;
#pragma unroll
      for (int e = 0; e < 8; ++e) {
        const int j = kk * 32 + lg * 8 + e;
        vb[e] = *(const short*)(Vs + j * 128 +
                                (((16 * w + l4) * 2) ^ (((j >> 3) & 7) << 4)));
      }
      apv = mfma16(pa, vb, apv);
    }
  }

  // ---- rowsum reduce -> inv ----
#pragma unroll
  for (int e = 0; e < 4; ++e) {
    float t = rsP[e];
    t += __shfl_xor(t, 1);
    t += __shfl_xor(t, 2);
    t += __shfl_xor(t, 4);
    t += __shfl_xor(t, 8);
    if (l4 == 0) rsumLds[w * 16 + lg * 4 + e] = t;
  }
  __syncthreads();
  if (tid < 16)
    invLds[tid] = 1.0f / (rsumLds[tid] + rsumLds[16 + tid] + rsumLds[32 + tid] +
                          rsumLds[48 + tid]);
  __syncthreads();
  float inv_e[4];
#pragma unroll
  for (int e = 0; e < 4; ++e) inv_e[e] = invLds[lg * 4 + e];

  // ================= WRITEBACK PHASE (normalized attn) =================
  const int r2 = tid >> 4, c2 = tid & 15;  // read/writeback mapping
#pragma unroll
  for (int jt = 0; jt < 8; ++jt) {
    const int j0 = jt * 128;
    __syncthreads();  // protect Ps from previous iteration's readers
#pragma unroll
    for (int e = 0; e < 4; ++e) {
      const int i = lg * 4 + e;
      const float p0 = bf2f(p_reg[jt][e]) * inv_e[e];
      const float p1 = bf2f(p_reg[jt][4 + e]) * inv_e[e];
      *(ushort*)(Ps + i * 256 + ((jl0 * 2) ^ ((i & 7) << 4))) = rne_bf16(p0);
      *(ushort*)(Ps + i * 256 + ((jl1 * 2) ^ ((i & 7) << 4))) = rne_bf16(p1);
    }
    __syncthreads();  // normalized P ready
    const bfrag pb =
        *(const bfrag*)(Ps + r2 * 256 + ((c2 * 16) ^ ((r2 & 7) << 4)));
    f4v f0, f1;
    f0.x = bf2f((ushort)pb[0]); f0.y = bf2f((ushort)pb[1]);
    f0.z = bf2f((ushort)pb[2]); f0.w = bf2f((ushort)pb[3]);
    f1.x = bf2f((ushort)pb[4]); f1.y = bf2f((ushort)pb[5]);
    f1.z = bf2f((ushort)pb[6]); f1.w = bf2f((ushort)pb[7]);
    float* gp = attn + attn_base + (size_t)r2 * Sn + j0 + c2 * 8;
    *(f4v*)gp = f0;
    *(f4v*)(gp + 4) = f1;
  }

  // ---- ctx epilogue: scale by inv, hi/lo bf16 split ----
#pragma unroll
  for (int e = 0; e < 4; ++e) {
    const int i = lg * 4 + e;
    const size_t o = (size_t)(b * Sn + i0 + i) * Dn + h * DHn + 16 * w + l4;
    ushort h16, l16;
    bsplit(apv[e] * inv_e[e], h16, l16);
    ctx_hi[o] = h16;
    ctx_lo[o] = l16;
  }
}

// ---------------------------------------------------------------------------
// LayerNorm over last dim (768), one block per row.
// ---------------------------------------------------------------------------
__global__ __launch_bounds__(256) void ln_kernel(
    const float* __restrict__ xin, const float* __restrict__ gamma,
    const float* __restrict__ beta, float* __restrict__ out) {
  const int row = blockIdx.x;
  const float* xr = xin + (size_t)row * Dn;
  const int tid = threadIdx.x;
  const float v0 = xr[tid];
  const float v1 = xr[tid + 256];
  const float v2 = xr[tid + 512];
  float s = v0 + v1 + v2;
  float s2 = v0 * v0 + v1 * v1 + v2 * v2;
#pragma unroll
  for (int off = 32; off > 0; off >>= 1) {
    s += __shfl_xor(s, off);
    s2 += __shfl_xor(s2, off);
  }
  __shared__ float red[2][4];
  const int w = tid >> 6, l = tid & 63;
  if (l == 0) { red[0][w] = s; red[1][w] = s2; }
  __syncthreads();
  s = red[0][0] + red[0][1] + red[0][2] + red[0][3];
  s2 = red[1][0] + red[1][1] + red[1][2] + red[1][3];
  const float mu = s * (1.f / 768.f);
  const float var = s2 * (1.f / 768.f) - mu * mu;
  const float inv = 1.0f / sqrtf(var + 1e-6f);
  out[(size_t)row * Dn + tid] = (v0 - mu) * inv * gamma[tid] + beta[tid];
  out[(size_t)row * Dn + tid + 256] =
      (v1 - mu) * inv * gamma[tid + 256] + beta[tid + 256];
  out[(size_t)row * Dn + tid + 512] =
      (v2 - mu) * inv * gamma[tid + 512] + beta[tid + 512];
}

}  // namespace

extern "C" void kernel_launch(void* const* d_in, const int* in_sizes, int n_in,
                              void* d_out, int out_size, void* d_ws,
                              size_t ws_size, hipStream_t stream) {
  const float* x = (const float*)d_in[0];
  const float* mask = (const float*)d_in[2];
  const float* adjoin = (const float*)d_in[3];
  const float* Wq = (const float*)d_in[4];
  const float* bq = (const float*)d_in[5];
  const float* Wk = (const float*)d_in[6];
  const float* bk = (const float*)d_in[7];
  const float* Wv = (const float*)d_in[8];
  const float* bv = (const float*)d_in[9];
  const float* Wo = (const float*)d_in[10];
  const float* bo = (const float*)d_in[11];
  const float* W1 = (const float*)d_in[12];
  const float* b1 = (const float*)d_in[13];
  const float* W2 = (const float*)d_in[14];
  const float* b2 = (const float*)d_in[15];
  const float* gamma2 = (const float*)d_in[16];
  const float* beta2 = (const float*)d_in[17];

  float* out2 = (float*)d_out;               // [B,S,D]
  float* attn = out2 + (size_t)Mrows * Dn;   // [B,H,S,S]

  // ---- workspace layout (bytes) ----
  char* ws = (char*)d_ws;
  const size_t BFS = (size_t)Mrows * Dn * 2;   // 12,582,912 (bf16 token map)
  const size_t F32S = (size_t)Mrows * Dn * 4;  // 25,165,824
  ushort* q_hi = (ushort*)(ws);
  ushort* k_sw = (ushort*)(ws + BFS);
  ushort* v_sw = (ushort*)(ws + 2 * BFS);
  ushort* ctx_hi = (ushort*)(ws + 3 * BFS + F32S);
  ushort* ctx_lo = (ushort*)(ws + 4 * BFS + F32S);
  float* out1 = (float*)(ws + 5 * BFS + F32S);
  ushort* out1_hi = (ushort*)(ws);                  // over q_hi (dead)
  ushort* out1_lo = (ushort*)(ws + BFS);            // over k_sw (dead)
  ushort* h_hi = (ushort*)(ws + 2 * BFS);           // over v_sw..ctx_hi
  const size_t WDD = (size_t)Dn * Dn * 2;           // 1.18 MB
  const size_t WDF = (size_t)Dn * Fn * 2;           // 4.72 MB
  char* wsW = ws + 5 * BFS + 2 * F32S;
  ushort* wot_hi = (ushort*)(wsW);
  ushort* wot_lo = (ushort*)(wsW + WDD);

  // ---- d_out scratch: out2 region dead until ln (step 8) ----
  char* o2r = (char*)out2;
  ushort* w1t_hi = (ushort*)(o2r);
  ushort* w1t_lo = (ushort*)(o2r + WDF);
  ushort* w2t_hi = (ushort*)(o2r + 2 * WDF);
  ushort* w2t_lo = (ushort*)(o2r + 3 * WDF);

  // ---- d_out scratch: attn region dead until attn_kernel (step 3) ----
  char* scr = (char*)attn;
  ushort* x_hi = (ushort*)(scr);
  ushort* x_lo = (ushort*)(scr + BFS);
  ushort* wqt_hi = (ushort*)(scr + 2 * BFS);
  ushort* wqt_lo = (ushort*)(scr + 2 * BFS + WDD);
  ushort* wkt_hi = (ushort*)(scr + 2 * BFS + 2 * WDD);
  ushort* wkt_lo = (ushort*)(scr + 2 * BFS + 3 * WDD);
  ushort* wvt_hi = (ushort*)(scr + 2 * BFS + 4 * WDD);
  ushort* wvt_lo = (ushort*)(scr + 2 * BFS + 5 * WDD);

  const dim3 blk(256);

  // 1) input splits + weight transpose-splits
  split_rows<<<dim3(2048), blk, 0, stream>>>((const float4*)x, x_hi, x_lo,
                                             Mrows * Dn / 4);
  transpose_split<<<dim3(12, 12), blk, 0, stream>>>(Wq, wqt_hi, wqt_lo, Dn, Dn);
  transpose_split<<<dim3(12, 12), blk, 0, stream>>>(Wk, wkt_hi, wkt_lo, Dn, Dn);
  transpose_split<<<dim3(12, 12), blk, 0, stream>>>(Wv, wvt_hi, wvt_lo, Dn, Dn);
  transpose_split<<<dim3(12, 12), blk, 0, stream>>>(Wo, wot_hi, wot_lo, Dn, Dn);
  transpose_split<<<dim3(48, 12), blk, 0, stream>>>(W1, w1t_hi, w1t_lo, Dn, Fn);
  transpose_split<<<dim3(12, 48), blk, 0, stream>>>(W2, w2t_hi, w2t_lo, Fn, Dn);

  // 2) fused QKV projection -> q plain, k/v pre-swizzled bf16
  mfma_gemm<0, true><<<dim3(18, 64), blk, 0, stream>>>(
      x_hi, x_lo, wqt_hi, wqt_lo, wkt_hi, wkt_lo, wvt_hi, wvt_lo, bq, bk, bv,
      nullptr, nullptr, nullptr, nullptr, q_hi, k_sw, v_sw, Dn);

  // 3) flash attention v5 (single pass; attn normalized; ctx hi/lo fused)
  attn_kernel<<<dim3(Sn / 16, Bn * Hn), blk, 0, stream>>>(
      q_hi, k_sw, v_sw, mask, adjoin, attn, ctx_hi, ctx_lo);

  // 5) out1 = x + ctx @ Wo + bo  (+ hi/lo split)
  mfma_gemm<1, true><<<dim3(6, 64), blk, 0, stream>>>(
      ctx_hi, ctx_lo, wot_hi, wot_lo, nullptr, nullptr, nullptr, nullptr, bo,
      nullptr, nullptr, x, out1, out1_hi, out1_lo, nullptr, nullptr, nullptr,
      Dn);

  // 6) h_hi = bf16(gelu(out1 @ W1 + b1))
  mfma_gemm<2, true><<<dim3(24, 64), blk, 0, stream>>>(
      out1_hi, out1_lo, w1t_hi, w1t_lo, nullptr, nullptr, nullptr, nullptr, b1,
      nullptr, nullptr, nullptr, nullptr, h_hi, nullptr, nullptr, nullptr,
      nullptr, Dn);

  // 7) out1 += h @ W2 + b2 (in place; A single-bf16)
  mfma_gemm<3, false><<<dim3(6, 64), blk, 0, stream>>>(
      h_hi, nullptr, w2t_hi, w2t_lo, nullptr, nullptr, nullptr, nullptr, b2,
      nullptr, nullptr, out1, out1, nullptr, nullptr, nullptr, nullptr,
      nullptr, Fn);

  // 8) out2 = layernorm(out1)
  ln_kernel<<<dim3(Mrows), blk, 0, stream>>>(out1, gamma2, beta2, out2);
}